// Round 5
// baseline (269.235 us; speedup 1.0000x reference)
//
#include <hip/hip_runtime.h>
#include <hip/hip_bf16.h>

// GroupedVectorSA (gfx950) — ROUND 17: barrier-free k_main.
// 256 thr (4 waves), 4 points/block, ONE wave per point, grid 2048.
// Every phase wave-local (private LDS slice); ZERO __syncthreads.
// launch_bounds(256,2) -> 256 VGPR budget: acc[16]+hfr[8]+k/q prefetch in regs.
// LDS 74KB -> 2 blocks/CU (8 waves/CU). Same MFMA count per point as R15.

typedef __attribute__((ext_vector_type(8))) short bf16x8_t;
typedef __attribute__((ext_vector_type(4))) float f32x4_t;

#define BN_EPS 1e-5f
#define WSYNC() asm volatile("s_waitcnt lgkmcnt(0)" ::: "memory")

__device__ __forceinline__ float blo(unsigned int v) {
    union { unsigned int u; float f; } x; x.u = v << 16; return x.f;
}
__device__ __forceinline__ float bhi(unsigned int v) {
    union { unsigned int u; float f; } x; x.u = v & 0xffff0000u; return x.f;
}
__device__ __forceinline__ unsigned int fbits(float f) {
    union { float f; unsigned int u; } x; x.f = f; return x.u;
}
__device__ __forceinline__ unsigned short f2b(float f) {      // RNE fp32->bf16
    unsigned int u = fbits(f);
    return (unsigned short)((u + 0x7fffu + ((u >> 16) & 1u)) >> 16);
}
__device__ __forceinline__ float b2f(unsigned short h) {      // bf16->fp32 exact
    union { unsigned int u; float f; } x; x.u = ((unsigned int)h) << 16; return x.f;
}
__device__ __forceinline__ unsigned int f2bpk(float a, float b) {  // hw packed cvt
    union { __hip_bfloat162 h; unsigned int u; } x;
    x.h = __float22bfloat162_rn(make_float2(a, b));
    return x.u;
}
__device__ __forceinline__ unsigned int relpair(unsigned int kb, unsigned int qb,
                                                unsigned int pm_, unsigned int pb_) {
    float r0 = (blo(kb) - blo(qb)) * blo(pm_) + blo(pb_);
    float r1 = (bhi(kb) - bhi(qb)) * bhi(pm_) + bhi(pb_);
    return f2bpk(r0, r1);
}

// ---------------------------------------------------------------------------
// K0: blocks 0..159: 5 weights -> bf16 fragment-linear. 160: W1 frags.
//     161: we1TF + qkv scale/shift + we BN fold (SSE).
// ---------------------------------------------------------------------------
__global__ __launch_bounds__(256) void k_prep(
    const float* __restrict__ wq, const float* __restrict__ wk,
    const float* __restrict__ wv, const float* __restrict__ pm2,
    const float* __restrict__ pb2,
    const float* __restrict__ pm_w1, const float* __restrict__ pm_b1,
    const float* __restrict__ pm_bn,
    const float* __restrict__ pb_w1, const float* __restrict__ pb_b1,
    const float* __restrict__ pb_bn,
    const float* __restrict__ we_w1,
    const float* __restrict__ bq, const float* __restrict__ bnq,
    const float* __restrict__ bk, const float* __restrict__ bnk,
    const float* __restrict__ bv,
    const float* __restrict__ we_b1, const float* __restrict__ we_bn,
    const float* __restrict__ we_b2,
    unsigned short* __restrict__ wsT, unsigned short* __restrict__ w1F,
    unsigned short* __restrict__ we1TF, float* __restrict__ SS)
{
    const int bid = blockIdx.x, t = threadIdx.x;
    if (bid < 160) {
        __shared__ unsigned short T[32][72];
        const int mat = bid >> 5;
        const int kk  = (bid >> 2) & 7;
        const int ntq = bid & 3;
        const float* s = (mat == 0) ? wq : (mat == 1) ? wk : (mat == 2) ? wv
                         : (mat == 3) ? pm2 : pb2;
        {
            int c = t & 63, r0 = t >> 6;
            for (int i = 0; i < 8; ++i) {
                int r = r0 + i * 4;
                T[r][c] = f2b(s[(kk * 32 + r) * 256 + ntq * 64 + c]);
            }
        }
        __syncthreads();
        {
            int seg = t >> 6, lane = t & 63;
            int col = seg * 16 + (lane & 15);
            int kr  = (lane >> 4) * 8;
            unsigned int v[8];
            #pragma unroll
            for (int j = 0; j < 8; ++j) v[j] = T[kr + j][col];
            uint4 o;
            o.x = v[0] | (v[1] << 16);
            o.y = v[2] | (v[3] << 16);
            o.z = v[4] | (v[5] << 16);
            o.w = v[6] | (v[7] << 16);
            *(uint4*)(wsT + mat * 65536 + (ntq * 4 + seg) * 4096 + kk * 512 + lane * 8) = o;
        }
    } else if (bid == 160) {
        // Build W1 B-fragments (K-slot packed, BN folded), pass0=pm, pass1=pb.
        int c = t;                      // column 0..255
        int nt = c >> 4, l15 = c & 15;
        float sm = pm_bn[c] / sqrtf(pm_bn[768 + c] + BN_EPS);
        float sb = pb_bn[c] / sqrtf(pb_bn[768 + c] + BN_EPS);
        float W[2][4];
        W[0][0] = pm_w1[c] * sm; W[0][1] = pm_w1[256 + c] * sm;
        W[0][2] = pm_w1[512 + c] * sm;
        W[0][3] = (pm_b1[c] - pm_bn[512 + c]) * sm + pm_bn[256 + c];
        W[1][0] = pb_w1[c] * sb; W[1][1] = pb_w1[256 + c] * sb;
        W[1][2] = pb_w1[512 + c] * sb;
        W[1][3] = (pb_b1[c] - pb_bn[512 + c]) * sb + pb_bn[256 + c];
        for (int pass = 0; pass < 2; ++pass) {
            unsigned short xh = f2b(W[pass][0]), xl = f2b(W[pass][0] - b2f(xh));
            unsigned short yh = f2b(W[pass][1]), yl = f2b(W[pass][1] - b2f(yh));
            unsigned short zh = f2b(W[pass][2]), zl = f2b(W[pass][2] - b2f(zh));
            unsigned short bh = f2b(W[pass][3]), bl = f2b(W[pass][3] - b2f(bh));
            unsigned short sl[16] = { xh, xh, xl, yh, yh, yl, zh, zh, zl,
                                      bh, bl, 0, 0, 0, 0, 0 };
            for (int q = 0; q < 4; ++q)
                for (int j = 0; j < 8; ++j)
                    w1F[((pass * 16 + nt) * 64 + q * 16 + l15) * 8 + j] =
                        (q < 2) ? sl[q * 8 + j] : (unsigned short)0;
        }
    } else {
        for (int j = 0; j < 8; ++j) {
            int e = t * 8 + j;
            int g = e >> 8, c = e & 255;
            we1TF[g * 256 + c] = f2b(we_w1[c * 8 + g]);
        }
        // qkv epilogue scale/shift fold: y = raw*sc + sh (relu for q,k)
        int c = t;
        float sq = bnq[c] / sqrtf(bnq[768 + c] + BN_EPS);
        SS[c]        = sq;
        SS[256 + c]  = (bq[c] - bnq[512 + c]) * sq + bnq[256 + c];
        float sk = bnk[c] / sqrtf(bnk[768 + c] + BN_EPS);
        SS[512 + c]  = sk;
        SS[768 + c]  = (bk[c] - bnk[512 + c]) * sk + bnk[256 + c];
        SS[1024 + c] = 1.0f;
        SS[1280 + c] = bv[c];
        // we BN fold: SSE = SS+1536: swe8[8], dwe8[8], web2[8]
        if (t < 8) {
            float s = we_bn[t] / sqrtf(we_bn[24 + t] + BN_EPS);
            SS[1536 + t] = s;
            SS[1544 + t] = (we_b1[t] - we_bn[16 + t]) * s + we_bn[8 + t];
            SS[1552 + t] = we_b2[t];
        }
    }
}

// ---------------------------------------------------------------------------
// K1: q/k/v GEMM, operand-swapped -> direct reg->global store, one barrier.
// grid=768, blk=256.
// ---------------------------------------------------------------------------
__global__ __launch_bounds__(256) void k_qkv(
    const float* __restrict__ feats,
    const unsigned short* __restrict__ wT,
    const float* __restrict__ SS,
    unsigned short* __restrict__ qkv)
{
    __shared__ unsigned short A[32][264];
    const int t    = threadIdx.x;
    const int widx = blockIdx.x >> 8;
    const int mb   = blockIdx.x & 255;

    for (int i = 0; i < 8; ++i) {
        int row = 4 * i + (t >> 6), col = (t & 63) * 4;
        float4 f = *(const float4*)(feats + (mb * 32 + row) * 256 + col);
        *(uint2*)&A[row][col] = make_uint2(f2bpk(f.x, f.y), f2bpk(f.z, f.w));
    }
    __syncthreads();

    const int lane = t & 63, w = t >> 6;
    const int ln15 = lane & 15, quad = lane >> 4;
    const int mt = w & 1, nh = w >> 1;

    bf16x8_t afr[8];
    #pragma unroll
    for (int kk = 0; kk < 8; ++kk)
        afr[kk] = *(const bf16x8_t*)&A[mt * 16 + ln15][kk * 32 + quad * 8];

    const unsigned short* W = wT + widx * 65536;
    unsigned short* dst = qkv + (size_t)widx * 8192 * 256;

    f32x4_t acc[8];
    for (int j = 0; j < 8; ++j) acc[j] = (f32x4_t){0.f, 0.f, 0.f, 0.f};

    #pragma unroll
    for (int kk = 0; kk < 8; ++kk) {
        #pragma unroll
        for (int j = 0; j < 8; ++j) {
            int nt = nh * 8 + j;
            bf16x8_t wfr = *(const bf16x8_t*)(W + ((nt * 8 + kk) * 64 + lane) * 8);
            acc[j] = __builtin_amdgcn_mfma_f32_16x16x32_bf16(wfr, afr[kk], acc[j], 0, 0, 0);
        }
    }

    // D^T: lane holds channels n0..n0+3 (rows), point m = mt*16+ln15 (col).
    const float* S = SS + widx * 512;
    const int row = mb * 32 + mt * 16 + ln15;
    #pragma unroll
    for (int j = 0; j < 8; ++j) {
        int n0 = (nh * 8 + j) * 16 + quad * 4;
        float4 s4 = *(const float4*)(S + n0);
        float4 h4 = *(const float4*)(S + 256 + n0);
        float y0 = acc[j][0] * s4.x + h4.x;
        float y1 = acc[j][1] * s4.y + h4.y;
        float y2 = acc[j][2] * s4.z + h4.z;
        float y3 = acc[j][3] * s4.w + h4.w;
        if (widx < 2) {
            y0 = fmaxf(y0, 0.f); y1 = fmaxf(y1, 0.f);
            y2 = fmaxf(y2, 0.f); y3 = fmaxf(y3, 0.f);
        }
        *(uint2*)(dst + (size_t)row * 256 + n0) =
            make_uint2(f2bpk(y0, y1), f2bpk(y2, y3));
    }
}

// ---------------------------------------------------------------------------
// K2: fused main. 256 threads (4 waves), 4 points/block, ONE wave per point.
// grid=2048. Barrier-free: all phases wave-local on a private LDS slice.
// ---------------------------------------------------------------------------
__global__ __launch_bounds__(256, 2) void k_main(
    const float* __restrict__ coords,
    const int*   __restrict__ index,
    const unsigned short* __restrict__ qm,
    const unsigned short* __restrict__ km,
    const unsigned short* __restrict__ vm,
    const unsigned short* __restrict__ pmw2F,
    const unsigned short* __restrict__ pbw2F,
    const unsigned short* __restrict__ w1F,
    const unsigned short* __restrict__ we1TF,
    const float* __restrict__ pm_b2, const float* __restrict__ pb_b2,
    const float* __restrict__ we_w2, const float* __restrict__ SSE,
    float* __restrict__ out)
{
    __shared__ unsigned short posX[4][16][32];   // pos K-slots (hi/lo packed)
    __shared__ unsigned short bufR[4][16][264];  // h_pb -> h_pm -> pem
    __shared__ unsigned short bufP[4][16][264];  // peb
    __shared__ float us_[4][16][12];             // uv -> logits -> softmax

    const int t = threadIdx.x;
    const int w = t >> 6, lane = t & 63;
    const int ln15 = lane & 15, quad = lane >> 4;
    const int Pg  = blockIdx.x * 4 + w;          // one wave = one point
    const int bb_ = Pg >> 12;
    const int rg  = (bb_ << 12) + index[Pg * 16 + ln15];

    // ---- stage posX own rows (lanes<16: row m=lane), wave-local ----
    if (lane < 16) {
        int m  = lane;
        int rs = (bb_ << 12) + index[Pg * 16 + m];
        float x = coords[Pg * 3 + 0] - coords[rs * 3 + 0];
        float y = coords[Pg * 3 + 1] - coords[rs * 3 + 1];
        float z = coords[Pg * 3 + 2] - coords[rs * 3 + 2];
        unsigned short xh = f2b(x), xl = f2b(x - b2f(xh));
        unsigned short yh = f2b(y), yl = f2b(y - b2f(yh));
        unsigned short zh = f2b(z), zl = f2b(z - b2f(zh));
        const unsigned short one = 0x3f80;
        posX[w][m][0] = xh; posX[w][m][1] = xl; posX[w][m][2] = xh;
        posX[w][m][3] = yh; posX[w][m][4] = yl; posX[w][m][5] = yh;
        posX[w][m][6] = zh; posX[w][m][7] = zl; posX[w][m][8] = zh;
        posX[w][m][9] = one; posX[w][m][10] = one;
        #pragma unroll
        for (int j2 = 11; j2 < 32; ++j2) posX[w][m][j2] = 0;
    }
    WSYNC();

    // ---- pos fragment (B-operand of swapped h-MFMAs) ----
    const bf16x8_t afrP = *(const bf16x8_t*)&posX[w][ln15][quad * 8];
    const f32x4_t zz = (f32x4_t){0.f, 0.f, 0.f, 0.f};

    // ---- h_pb = relu(pos @ W1pb): 16 MFMA -> bufR ----
    f32x4_t hacc[16];
    #pragma unroll
    for (int nt = 0; nt < 16; ++nt) {
        bf16x8_t wfr = *(const bf16x8_t*)(w1F + ((16 + nt) * 64 + lane) * 8);
        hacc[nt] = __builtin_amdgcn_mfma_f32_16x16x32_bf16(wfr, afrP, zz, 0, 0, 0);
    }
    #pragma unroll
    for (int nt = 0; nt < 16; ++nt) {
        unsigned int pk0 = f2bpk(fmaxf(hacc[nt][0], 0.f), fmaxf(hacc[nt][1], 0.f));
        unsigned int pk1 = f2bpk(fmaxf(hacc[nt][2], 0.f), fmaxf(hacc[nt][3], 0.f));
        *(uint2*)&bufR[w][ln15][nt * 16 + quad * 4] = make_uint2(pk0, pk1);
    }
    WSYNC();

    // ---- peb = h_pb @ w2pb + b2: h-frags in regs, 128 MFMA ----
    bf16x8_t hfr[8];
    #pragma unroll
    for (int kk = 0; kk < 8; ++kk)
        hfr[kk] = *(const bf16x8_t*)&bufR[w][ln15][kk * 32 + quad * 8];
    f32x4_t acc[16];
    #pragma unroll
    for (int nt = 0; nt < 16; ++nt)
        acc[nt] = *(const f32x4_t*)(pb_b2 + nt * 16 + quad * 4);
    #pragma unroll
    for (int kk = 0; kk < 8; ++kk) {
        #pragma unroll
        for (int nt = 0; nt < 16; ++nt) {
            bf16x8_t wfr = *(const bf16x8_t*)(pbw2F + ((nt * 8 + kk) * 64 + lane) * 8);
            acc[nt] = __builtin_amdgcn_mfma_f32_16x16x32_bf16(wfr, hfr[kk], acc[nt], 0, 0, 0);
        }
    }
    #pragma unroll
    for (int nt = 0; nt < 16; ++nt) {
        unsigned int pk0 = f2bpk(acc[nt][0], acc[nt][1]);
        unsigned int pk1 = f2bpk(acc[nt][2], acc[nt][3]);
        *(uint2*)&bufP[w][ln15][nt * 16 + quad * 4] = make_uint2(pk0, pk1);
    }

    // ---- h_pm = relu(pos @ W1pm): 16 MFMA (reuse hacc) ----
    #pragma unroll
    for (int nt = 0; nt < 16; ++nt) {
        bf16x8_t wfr = *(const bf16x8_t*)(w1F + (nt * 64 + lane) * 8);
        hacc[nt] = __builtin_amdgcn_mfma_f32_16x16x32_bf16(wfr, afrP, zz, 0, 0, 0);
    }
    WSYNC();                                    // hfr reads drained
    #pragma unroll
    for (int nt = 0; nt < 16; ++nt) {
        unsigned int pk0 = f2bpk(fmaxf(hacc[nt][0], 0.f), fmaxf(hacc[nt][1], 0.f));
        unsigned int pk1 = f2bpk(fmaxf(hacc[nt][2], 0.f), fmaxf(hacc[nt][3], 0.f));
        *(uint2*)&bufR[w][ln15][nt * 16 + quad * 4] = make_uint2(pk0, pk1);
    }
    WSYNC();

    // ---- pem = h_pm @ w2pm + b2: 128 MFMA ----
    bf16x8_t hfr2[8];
    #pragma unroll
    for (int kk = 0; kk < 8; ++kk)
        hfr2[kk] = *(const bf16x8_t*)&bufR[w][ln15][kk * 32 + quad * 8];
    #pragma unroll
    for (int nt = 0; nt < 16; ++nt)
        acc[nt] = *(const f32x4_t*)(pm_b2 + nt * 16 + quad * 4);
    #pragma unroll
    for (int kk = 0; kk < 8; ++kk) {
        #pragma unroll
        for (int nt = 0; nt < 16; ++nt) {
            bf16x8_t wfr = *(const bf16x8_t*)(pmw2F + ((nt * 8 + kk) * 64 + lane) * 8);
            acc[nt] = __builtin_amdgcn_mfma_f32_16x16x32_bf16(wfr, hfr2[kk], acc[nt], 0, 0, 0);
        }
    }

    // ---- k/q prefetch (issued under pem epilogue) ----
    uint4 kpre[8], qpre[8];
    #pragma unroll
    for (int kk = 0; kk < 8; ++kk) {
        kpre[kk] = *(const uint4*)(km + (size_t)rg * 256 + kk * 32 + quad * 8);
        qpre[kk] = *(const uint4*)(qm + (size_t)Pg * 256 + kk * 32 + quad * 8);
    }

    // pem epilogue -> bufR (hfr2 reads already consumed by MFMAs)
    #pragma unroll
    for (int nt = 0; nt < 16; ++nt) {
        unsigned int pk0 = f2bpk(acc[nt][0], acc[nt][1]);
        unsigned int pk1 = f2bpk(acc[nt][2], acc[nt][3]);
        *(uint2*)&bufR[w][ln15][nt * 16 + quad * 4] = make_uint2(pk0, pk1);
    }
    WSYNC();

    // ---- relation + logits (full K): 8 MFMA ----
    {
        const bf16x8_t bz = {0, 0, 0, 0, 0, 0, 0, 0};
        f32x4_t lacc = zz;
        #pragma unroll
        for (int kk = 0; kk < 8; ++kk) {
            int cb8 = kk * 32 + quad * 8;
            uint4 pm4 = *(const uint4*)&bufR[w][ln15][cb8];
            uint4 pb4 = *(const uint4*)&bufP[w][ln15][cb8];
            union { uint4 u; bf16x8_t v; } rr;
            rr.u.x = relpair(kpre[kk].x, qpre[kk].x, pm4.x, pb4.x);
            rr.u.y = relpair(kpre[kk].y, qpre[kk].y, pm4.y, pb4.y);
            rr.u.z = relpair(kpre[kk].z, qpre[kk].z, pm4.z, pb4.z);
            rr.u.w = relpair(kpre[kk].w, qpre[kk].w, pm4.w, pb4.w);
            bf16x8_t wfr = bz;
            if (ln15 < 8) wfr = *(const bf16x8_t*)(we1TF + ln15 * 256 + cb8);
            lacc = __builtin_amdgcn_mfma_f32_16x16x32_bf16(wfr, rr.v, lacc, 0, 0, 0);
        }
        // D[g=quad*4+r][s=ln15], rows g<8 valid -> quad<2. BN+relu in-reg.
        if (quad < 2) {
            f32x4_t uv4;
            #pragma unroll
            for (int r = 0; r < 4; ++r) {
                int g = quad * 4 + r;
                uv4[r] = fmaxf(lacc[r] * SSE[g] + SSE[8 + g], 0.f);
            }
            *(f32x4_t*)&us_[w][ln15][quad * 4] = uv4;
        }
    }

    // ---- v-gather prefetch (4 cols/lane; rows via shfl) ----
    const int c4 = lane * 4;
    uint2 vpre[16];
    #pragma unroll
    for (int s = 0; s < 16; ++s) {
        int rv = __shfl(rg, s);
        vpre[s] = *(const uint2*)(vm + (size_t)rv * 256 + c4);
    }
    WSYNC();

    // ---- logits2 (lanes<16 = s) ----
    if (lane < 16) {
        int s = lane;
        float uvv[8], l[8];
        #pragma unroll
        for (int g = 0; g < 8; ++g) uvv[g] = us_[w][s][g];
        #pragma unroll
        for (int g = 0; g < 8; ++g) {
            float x = SSE[16 + g];
            #pragma unroll
            for (int gp = 0; gp < 8; ++gp) x += uvv[gp] * we_w2[gp * 8 + g];
            l[g] = x;
        }
        #pragma unroll
        for (int g = 0; g < 8; ++g) us_[w][s][g] = l[g];
    }
    WSYNC();

    // ---- softmax over s (lanes<8 = g) ----
    if (lane < 8) {
        int g = lane;
        float mx = -1e30f;
        for (int s = 0; s < 16; ++s) mx = fmaxf(mx, us_[w][s][g]);
        float e[16], sum = 0.f;
        for (int s = 0; s < 16; ++s) { e[s] = __expf(us_[w][s][g] - mx); sum += e[s]; }
        float inv = 1.f / sum;
        for (int s = 0; s < 16; ++s) us_[w][s][g] = e[s] * inv;
    }
    WSYNC();

    // ---- output: 64 lanes x 4 cols ----
    {
        int g = lane >> 3;
        float a0 = 0.f, a1 = 0.f, a2 = 0.f, a3 = 0.f;
        #pragma unroll
        for (int s = 0; s < 16; ++s) {
            float wv_ = us_[w][s][g];
            uint2 v2 = vpre[s];
            uint2 p2 = *(const uint2*)&bufP[w][s][c4];
            a0 += wv_ * (blo(v2.x) + blo(p2.x));
            a1 += wv_ * (bhi(v2.x) + bhi(p2.x));
            a2 += wv_ * (blo(v2.y) + blo(p2.y));
            a3 += wv_ * (bhi(v2.y) + bhi(p2.y));
        }
        *(float4*)(out + (size_t)Pg * 256 + c4) = make_float4(a0, a1, a2, a3);
    }
}

// ---------------------------------------------------------------------------
extern "C" void kernel_launch(void* const* d_in, const int* in_sizes, int n_in,
                              void* d_out, int out_size, void* d_ws, size_t ws_size,
                              hipStream_t stream)
{
    const float* feats  = (const float*)d_in[0];
    const float* coords = (const float*)d_in[1];
    const int*   index  = (const int*)d_in[2];
    const float* wq     = (const float*)d_in[3];
    const float* bq     = (const float*)d_in[4];
    const float* bnq    = (const float*)d_in[5];
    const float* wk     = (const float*)d_in[6];
    const float* bk     = (const float*)d_in[7];
    const float* bnk    = (const float*)d_in[8];
    const float* wv     = (const float*)d_in[9];
    const float* bv     = (const float*)d_in[10];
    const float* pm_w1  = (const float*)d_in[11];
    const float* pm_b1  = (const float*)d_in[12];
    const float* pm_bn  = (const float*)d_in[13];
    const float* pm_w2  = (const float*)d_in[14];
    const float* pm_b2  = (const float*)d_in[15];
    const float* pb_w1  = (const float*)d_in[16];
    const float* pb_b1  = (const float*)d_in[17];
    const float* pb_bn  = (const float*)d_in[18];
    const float* pb_w2  = (const float*)d_in[19];
    const float* pb_b2  = (const float*)d_in[20];
    const float* we_w1  = (const float*)d_in[21];
    const float* we_b1  = (const float*)d_in[22];
    const float* we_bn  = (const float*)d_in[23];
    const float* we_w2  = (const float*)d_in[24];
    const float* we_b2  = (const float*)d_in[25];

    unsigned short* qkv   = (unsigned short*)d_ws;
    unsigned short* wsT   = qkv + (size_t)3 * 8192 * 256;
    unsigned short* we1TF = wsT + 5 * 65536;
    unsigned short* w1F   = we1TF + 2048;
    float*          SS    = (float*)(w1F + 16384);

    const size_t need = (size_t)13281376;
    if (ws_size < need) {
        hipMemsetAsync(d_out, 0, (size_t)out_size * 4, stream);
        return;
    }

    k_prep<<<162,  256, 0, stream>>>(wq, wk, wv, pm_w2, pb_w2,
                                     pm_w1, pm_b1, pm_bn,
                                     pb_w1, pb_b1, pb_bn,
                                     we_w1,
                                     bq, bnq, bk, bnk, bv,
                                     we_b1, we_bn, we_b2,
                                     wsT, w1F, we1TF, SS);
    k_qkv <<<768,  256, 0, stream>>>(feats, wsT, SS, qkv);
    k_main<<<2048, 256, 0, stream>>>(coords, index,
                                     qkv,
                                     qkv + (size_t)8192 * 256,
                                     qkv + (size_t)2 * 8192 * 256,
                                     wsT + 3 * 65536,
                                     wsT + 4 * 65536,
                                     w1F, we1TF,
                                     pm_b2, pb_b2,
                                     we_w2, SS + 1536,
                                     (float*)d_out);
}

// Round 6
// 212.328 us; speedup vs baseline: 1.2680x; 1.2680x over previous
//
#include <hip/hip_runtime.h>
#include <hip/hip_bf16.h>

// GroupedVectorSA (gfx950) — ROUND 18: R15 structure, GEMM phases re-tiled
// nt-split x4 / mt-split x2 per wave (was nt x8): halves per-wave A-fragment
// LDS reads (the dominant pipe, ~46% busy), pays 2x weight L2 refetch (cheap).
// Relation/tail/barriers identical to R15 (78us). k_qkv = direct-store (R16).

typedef __attribute__((ext_vector_type(8))) short bf16x8_t;
typedef __attribute__((ext_vector_type(4))) float f32x4_t;

#define BN_EPS 1e-5f
#define WSYNC() asm volatile("s_waitcnt lgkmcnt(0)" ::: "memory")

__device__ __forceinline__ float blo(unsigned int v) {
    union { unsigned int u; float f; } x; x.u = v << 16; return x.f;
}
__device__ __forceinline__ float bhi(unsigned int v) {
    union { unsigned int u; float f; } x; x.u = v & 0xffff0000u; return x.f;
}
__device__ __forceinline__ unsigned int fbits(float f) {
    union { float f; unsigned int u; } x; x.f = f; return x.u;
}
__device__ __forceinline__ unsigned short f2b(float f) {      // RNE fp32->bf16
    unsigned int u = fbits(f);
    return (unsigned short)((u + 0x7fffu + ((u >> 16) & 1u)) >> 16);
}
__device__ __forceinline__ float b2f(unsigned short h) {      // bf16->fp32 exact
    union { unsigned int u; float f; } x; x.u = ((unsigned int)h) << 16; return x.f;
}
__device__ __forceinline__ unsigned int f2bpk(float a, float b) {  // hw packed cvt
    union { __hip_bfloat162 h; unsigned int u; } x;
    x.h = __float22bfloat162_rn(make_float2(a, b));
    return x.u;
}
__device__ __forceinline__ unsigned int relpair(unsigned int kb, unsigned int qb,
                                                unsigned int pm_, unsigned int pb_) {
    float r0 = (blo(kb) - blo(qb)) * blo(pm_) + blo(pb_);
    float r1 = (bhi(kb) - bhi(qb)) * bhi(pm_) + bhi(pb_);
    return f2bpk(r0, r1);
}

// ---------------------------------------------------------------------------
// K0: blocks 0..159: 5 weights -> bf16 fragment-linear. 160: W1 frags.
//     161: we1TF + qkv scale/shift fold.
// ---------------------------------------------------------------------------
__global__ __launch_bounds__(256) void k_prep(
    const float* __restrict__ wq, const float* __restrict__ wk,
    const float* __restrict__ wv, const float* __restrict__ pm2,
    const float* __restrict__ pb2,
    const float* __restrict__ pm_w1, const float* __restrict__ pm_b1,
    const float* __restrict__ pm_bn,
    const float* __restrict__ pb_w1, const float* __restrict__ pb_b1,
    const float* __restrict__ pb_bn,
    const float* __restrict__ we_w1,
    const float* __restrict__ bq, const float* __restrict__ bnq,
    const float* __restrict__ bk, const float* __restrict__ bnk,
    const float* __restrict__ bv,
    unsigned short* __restrict__ wsT, unsigned short* __restrict__ w1F,
    unsigned short* __restrict__ we1TF, float* __restrict__ SS)
{
    const int bid = blockIdx.x, t = threadIdx.x;
    if (bid < 160) {
        __shared__ unsigned short T[32][72];
        const int mat = bid >> 5;
        const int kk  = (bid >> 2) & 7;
        const int ntq = bid & 3;
        const float* s = (mat == 0) ? wq : (mat == 1) ? wk : (mat == 2) ? wv
                         : (mat == 3) ? pm2 : pb2;
        {
            int c = t & 63, r0 = t >> 6;
            for (int i = 0; i < 8; ++i) {
                int r = r0 + i * 4;
                T[r][c] = f2b(s[(kk * 32 + r) * 256 + ntq * 64 + c]);
            }
        }
        __syncthreads();
        {
            int seg = t >> 6, lane = t & 63;
            int col = seg * 16 + (lane & 15);
            int kr  = (lane >> 4) * 8;
            unsigned int v[8];
            #pragma unroll
            for (int j = 0; j < 8; ++j) v[j] = T[kr + j][col];
            uint4 o;
            o.x = v[0] | (v[1] << 16);
            o.y = v[2] | (v[3] << 16);
            o.z = v[4] | (v[5] << 16);
            o.w = v[6] | (v[7] << 16);
            *(uint4*)(wsT + mat * 65536 + (ntq * 4 + seg) * 4096 + kk * 512 + lane * 8) = o;
        }
    } else if (bid == 160) {
        // Build W1 B-fragments (K-slot packed, BN folded), pass0=pm, pass1=pb.
        int c = t;                      // column 0..255
        int nt = c >> 4, l15 = c & 15;
        float sm = pm_bn[c] / sqrtf(pm_bn[768 + c] + BN_EPS);
        float sb = pb_bn[c] / sqrtf(pb_bn[768 + c] + BN_EPS);
        float W[2][4];
        W[0][0] = pm_w1[c] * sm; W[0][1] = pm_w1[256 + c] * sm;
        W[0][2] = pm_w1[512 + c] * sm;
        W[0][3] = (pm_b1[c] - pm_bn[512 + c]) * sm + pm_bn[256 + c];
        W[1][0] = pb_w1[c] * sb; W[1][1] = pb_w1[256 + c] * sb;
        W[1][2] = pb_w1[512 + c] * sb;
        W[1][3] = (pb_b1[c] - pb_bn[512 + c]) * sb + pb_bn[256 + c];
        for (int pass = 0; pass < 2; ++pass) {
            unsigned short xh = f2b(W[pass][0]), xl = f2b(W[pass][0] - b2f(xh));
            unsigned short yh = f2b(W[pass][1]), yl = f2b(W[pass][1] - b2f(yh));
            unsigned short zh = f2b(W[pass][2]), zl = f2b(W[pass][2] - b2f(zh));
            unsigned short bh = f2b(W[pass][3]), bl = f2b(W[pass][3] - b2f(bh));
            unsigned short sl[16] = { xh, xh, xl, yh, yh, yl, zh, zh, zl,
                                      bh, bl, 0, 0, 0, 0, 0 };
            for (int q = 0; q < 4; ++q)
                for (int j = 0; j < 8; ++j)
                    w1F[((pass * 16 + nt) * 64 + q * 16 + l15) * 8 + j] =
                        (q < 2) ? sl[q * 8 + j] : (unsigned short)0;
        }
    } else {
        for (int j = 0; j < 8; ++j) {
            int e = t * 8 + j;
            int g = e >> 8, c = e & 255;
            we1TF[g * 256 + c] = f2b(we_w1[c * 8 + g]);
        }
        // qkv epilogue scale/shift fold: y = raw*sc + sh (relu for q,k)
        int c = t;
        float sq = bnq[c] / sqrtf(bnq[768 + c] + BN_EPS);
        SS[c]        = sq;
        SS[256 + c]  = (bq[c] - bnq[512 + c]) * sq + bnq[256 + c];
        float sk = bnk[c] / sqrtf(bnk[768 + c] + BN_EPS);
        SS[512 + c]  = sk;
        SS[768 + c]  = (bk[c] - bnk[512 + c]) * sk + bnk[256 + c];
        SS[1024 + c] = 1.0f;
        SS[1280 + c] = bv[c];
    }
}

// ---------------------------------------------------------------------------
// K1: q/k/v GEMM, operand-swapped -> direct reg->global store, one barrier.
// grid=768, blk=256.
// ---------------------------------------------------------------------------
__global__ __launch_bounds__(256) void k_qkv(
    const float* __restrict__ feats,
    const unsigned short* __restrict__ wT,
    const float* __restrict__ SS,
    unsigned short* __restrict__ qkv)
{
    __shared__ unsigned short A[32][264];
    const int t    = threadIdx.x;
    const int widx = blockIdx.x >> 8;
    const int mb   = blockIdx.x & 255;

    for (int i = 0; i < 8; ++i) {
        int row = 4 * i + (t >> 6), col = (t & 63) * 4;
        float4 f = *(const float4*)(feats + (mb * 32 + row) * 256 + col);
        *(uint2*)&A[row][col] = make_uint2(f2bpk(f.x, f.y), f2bpk(f.z, f.w));
    }
    __syncthreads();

    const int lane = t & 63, w = t >> 6;
    const int ln15 = lane & 15, quad = lane >> 4;
    const int mt = w & 1, nh = w >> 1;

    bf16x8_t afr[8];
    #pragma unroll
    for (int kk = 0; kk < 8; ++kk)
        afr[kk] = *(const bf16x8_t*)&A[mt * 16 + ln15][kk * 32 + quad * 8];

    const unsigned short* W = wT + widx * 65536;
    unsigned short* dst = qkv + (size_t)widx * 8192 * 256;

    f32x4_t acc[8];
    for (int j = 0; j < 8; ++j) acc[j] = (f32x4_t){0.f, 0.f, 0.f, 0.f};

    #pragma unroll
    for (int kk = 0; kk < 8; ++kk) {
        #pragma unroll
        for (int j = 0; j < 8; ++j) {
            int nt = nh * 8 + j;
            bf16x8_t wfr = *(const bf16x8_t*)(W + ((nt * 8 + kk) * 64 + lane) * 8);
            acc[j] = __builtin_amdgcn_mfma_f32_16x16x32_bf16(wfr, afr[kk], acc[j], 0, 0, 0);
        }
    }

    // D^T: lane holds channels n0..n0+3 (rows), point m = mt*16+ln15 (col).
    const float* S = SS + widx * 512;
    const int row = mb * 32 + mt * 16 + ln15;
    #pragma unroll
    for (int j = 0; j < 8; ++j) {
        int n0 = (nh * 8 + j) * 16 + quad * 4;
        float4 s4 = *(const float4*)(S + n0);
        float4 h4 = *(const float4*)(S + 256 + n0);
        float y0 = acc[j][0] * s4.x + h4.x;
        float y1 = acc[j][1] * s4.y + h4.y;
        float y2 = acc[j][2] * s4.z + h4.z;
        float y3 = acc[j][3] * s4.w + h4.w;
        if (widx < 2) {
            y0 = fmaxf(y0, 0.f); y1 = fmaxf(y1, 0.f);
            y2 = fmaxf(y2, 0.f); y3 = fmaxf(y3, 0.f);
        }
        *(uint2*)(dst + (size_t)row * 256 + n0) =
            make_uint2(f2bpk(y0, y1), f2bpk(y2, y3));
    }
}

// ---------------------------------------------------------------------------
// K2: fused main. 512 threads (8 waves), 4 points/block, wave pair per point.
// grid=2048. GEMM phases: wave w owns nt = (w>>1)*4+j (j<4), mt = (w&1)*2+i
// (i<2). Relation/tail as R15 (p = w>>1, sub = w&1).
// ---------------------------------------------------------------------------
__global__ __launch_bounds__(512, 4) void k_main(
    const float* __restrict__ coords,
    const int*   __restrict__ index,
    const unsigned short* __restrict__ qm,
    const unsigned short* __restrict__ km,
    const unsigned short* __restrict__ vm,
    const unsigned short* __restrict__ pmw2F,
    const unsigned short* __restrict__ pbw2F,
    const unsigned short* __restrict__ w1F,
    const unsigned short* __restrict__ we1TF,
    const float* __restrict__ pm_b2, const float* __restrict__ pb_b2,
    const float* __restrict__ we_b1, const float* __restrict__ we_bn,
    const float* __restrict__ we_w2, const float* __restrict__ we_b2,
    float* __restrict__ out)
{
    __shared__ unsigned short bufR[64][264];   // h_pb -> h_pm -> pem
    __shared__ unsigned short bufP[64][264];   // peb
    __shared__ unsigned short posX[64][32];    // B-operand K-slots (hi/lo packed)
    __shared__ float usP[2][64][8];            // partial logits (K-split halves)
    __shared__ float us_[64][8];               // logits -> softmax w
    __shared__ int   rowg_[64];
    __shared__ float we2s[8][8];
    __shared__ float web2[8], swe8[8], dwe8[8];

    const int t   = threadIdx.x;
    const int P0  = blockIdx.x * 4;
    const int bb_ = P0 >> 12;
    const int w = t >> 6, lane = t & 63;
    const int ln15 = lane & 15, quad = lane >> 4;
    const int p   = w >> 1, sub = w & 1;       // point p; sub = K-half / mt-half
    const int R0  = p * 16;
    const int Pg  = P0 + p;

    // ---- per-lane neighbor row (s=ln15) ----
    const int rg = (bb_ << 12) + index[Pg * 16 + ln15];

    // ---- stage posX K-slots (t<64 -> row m=t) + small consts ----
    if (t < 64) {
        int m  = t;
        int Pr = P0 + (m >> 4);
        int rs = (bb_ << 12) + index[Pr * 16 + (m & 15)];
        rowg_[m] = rs;
        float x = coords[Pr * 3 + 0] - coords[rs * 3 + 0];
        float y = coords[Pr * 3 + 1] - coords[rs * 3 + 1];
        float z = coords[Pr * 3 + 2] - coords[rs * 3 + 2];
        unsigned short xh = f2b(x), xl = f2b(x - b2f(xh));
        unsigned short yh = f2b(y), yl = f2b(y - b2f(yh));
        unsigned short zh = f2b(z), zl = f2b(z - b2f(zh));
        const unsigned short one = 0x3f80;
        posX[m][0] = xh; posX[m][1] = xl; posX[m][2] = xh;
        posX[m][3] = yh; posX[m][4] = yl; posX[m][5] = yh;
        posX[m][6] = zh; posX[m][7] = zl; posX[m][8] = zh;
        posX[m][9] = one; posX[m][10] = one;
        #pragma unroll
        for (int j2 = 11; j2 < 32; ++j2) posX[m][j2] = 0;
        we2s[m >> 3][m & 7] = we_w2[m];
    }
    if (t < 8) {
        float s = we_bn[t] / sqrtf(we_bn[24 + t] + BN_EPS);
        swe8[t] = s;
        dwe8[t] = (we_b1[t] - we_bn[16 + t]) * s + we_bn[8 + t];
        web2[t] = we_b2[t];
    }
    __syncthreads();                           // B1 (posX visible)

    // ---- pos fragments for this wave's 2 mt tiles ----
    bf16x8_t afrP[2];
    #pragma unroll
    for (int i = 0; i < 2; ++i)
        afrP[i] = *(const bf16x8_t*)&posX[(sub * 2 + i) * 16 + ln15][quad * 8];
    const f32x4_t zz = (f32x4_t){0.f, 0.f, 0.f, 0.f};

    // ---- h_pb = relu(pos @ W1pb): 4nt x 2mt -> bufR ----
    {
        f32x4_t hb[4][2];
        #pragma unroll
        for (int j = 0; j < 4; ++j) {
            bf16x8_t wfr = *(const bf16x8_t*)(w1F + ((16 + p * 4 + j) * 64 + lane) * 8);
            #pragma unroll
            for (int i = 0; i < 2; ++i)
                hb[j][i] = __builtin_amdgcn_mfma_f32_16x16x32_bf16(wfr, afrP[i], zz, 0, 0, 0);
        }
        #pragma unroll
        for (int j = 0; j < 4; ++j)
            #pragma unroll
            for (int i = 0; i < 2; ++i) {
                unsigned int pk0 = f2bpk(fmaxf(hb[j][i][0], 0.f), fmaxf(hb[j][i][1], 0.f));
                unsigned int pk1 = f2bpk(fmaxf(hb[j][i][2], 0.f), fmaxf(hb[j][i][3], 0.f));
                *(uint2*)&bufR[(sub * 2 + i) * 16 + ln15][(p * 4 + j) * 16 + quad * 4] =
                    make_uint2(pk0, pk1);
            }
    }
    __syncthreads();                           // B2 (h_pb visible)

    // ---- phase: peb MFMA + h_pm MFMA (held in accM) ----
    f32x4_t accM[4][2];                        // h_pm accumulators (held past B3)
    #pragma unroll
    for (int j = 0; j < 4; ++j) {
        bf16x8_t wfr = *(const bf16x8_t*)(w1F + ((p * 4 + j) * 64 + lane) * 8);
        #pragma unroll
        for (int i = 0; i < 2; ++i)
            accM[j][i] = __builtin_amdgcn_mfma_f32_16x16x32_bf16(wfr, afrP[i], zz, 0, 0, 0);
    }
    f32x4_t acc[4][2];
    #pragma unroll
    for (int j = 0; j < 4; ++j) {
        f32x4_t b = *(const f32x4_t*)(pb_b2 + (p * 4 + j) * 16 + quad * 4);
        acc[j][0] = b; acc[j][1] = b;
    }
    #pragma unroll
    for (int kk = 0; kk < 8; ++kk) {
        bf16x8_t hfr[2];
        #pragma unroll
        for (int i = 0; i < 2; ++i)
            hfr[i] = *(const bf16x8_t*)&bufR[(sub * 2 + i) * 16 + ln15][kk * 32 + quad * 8];
        #pragma unroll
        for (int j = 0; j < 4; ++j) {
            bf16x8_t wfr = *(const bf16x8_t*)(pbw2F + (((p * 4 + j) * 8 + kk) * 64 + lane) * 8);
            #pragma unroll
            for (int i = 0; i < 2; ++i)
                acc[j][i] = __builtin_amdgcn_mfma_f32_16x16x32_bf16(wfr, hfr[i], acc[j][i], 0, 0, 0);
        }
    }
    // peb epilogue -> bufP (free buffer, no barrier needed before write)
    #pragma unroll
    for (int j = 0; j < 4; ++j)
        #pragma unroll
        for (int i = 0; i < 2; ++i) {
            unsigned int pk0 = f2bpk(acc[j][i][0], acc[j][i][1]);
            unsigned int pk1 = f2bpk(acc[j][i][2], acc[j][i][3]);
            *(uint2*)&bufP[(sub * 2 + i) * 16 + ln15][(p * 4 + j) * 16 + quad * 4] =
                make_uint2(pk0, pk1);
        }
    __syncthreads();                           // B3 (bufR h_pb reads done)

    // ---- h_pm epilogue (relu+pack) -> bufR ----
    #pragma unroll
    for (int j = 0; j < 4; ++j)
        #pragma unroll
        for (int i = 0; i < 2; ++i) {
            unsigned int pk0 = f2bpk(fmaxf(accM[j][i][0], 0.f), fmaxf(accM[j][i][1], 0.f));
            unsigned int pk1 = f2bpk(fmaxf(accM[j][i][2], 0.f), fmaxf(accM[j][i][3], 0.f));
            *(uint2*)&bufR[(sub * 2 + i) * 16 + ln15][(p * 4 + j) * 16 + quad * 4] =
                make_uint2(pk0, pk1);
        }
    __syncthreads();                           // B4 (h_pm visible)

    // ---- pem MFMA + k-gather prefetch (K-half = sub) ----
    uint4 kpre[4];
    #pragma unroll
    for (int kk = 0; kk < 4; ++kk)
        kpre[kk] = *(const uint4*)(km + (size_t)rg * 256 + (sub * 4 + kk) * 32 + quad * 8);
    #pragma unroll
    for (int j = 0; j < 4; ++j) {
        f32x4_t b = *(const f32x4_t*)(pm_b2 + (p * 4 + j) * 16 + quad * 4);
        acc[j][0] = b; acc[j][1] = b;
    }
    #pragma unroll
    for (int kk = 0; kk < 8; ++kk) {
        bf16x8_t hfr[2];
        #pragma unroll
        for (int i = 0; i < 2; ++i)
            hfr[i] = *(const bf16x8_t*)&bufR[(sub * 2 + i) * 16 + ln15][kk * 32 + quad * 8];
        #pragma unroll
        for (int j = 0; j < 4; ++j) {
            bf16x8_t wfr = *(const bf16x8_t*)(pmw2F + (((p * 4 + j) * 8 + kk) * 64 + lane) * 8);
            #pragma unroll
            for (int i = 0; i < 2; ++i)
                acc[j][i] = __builtin_amdgcn_mfma_f32_16x16x32_bf16(wfr, hfr[i], acc[j][i], 0, 0, 0);
        }
    }
    __syncthreads();                           // B5 (bufR h_pm reads done)

    // ---- q prefetch (K-half) ----
    uint4 qpre[4];
    #pragma unroll
    for (int kk = 0; kk < 4; ++kk)
        qpre[kk] = *(const uint4*)(qm + (size_t)Pg * 256 + (sub * 4 + kk) * 32 + quad * 8);

    // pem epilogue -> bufR
    #pragma unroll
    for (int j = 0; j < 4; ++j)
        #pragma unroll
        for (int i = 0; i < 2; ++i) {
            unsigned int pk0 = f2bpk(acc[j][i][0], acc[j][i][1]);
            unsigned int pk1 = f2bpk(acc[j][i][2], acc[j][i][3]);
            *(uint2*)&bufR[(sub * 2 + i) * 16 + ln15][(p * 4 + j) * 16 + quad * 4] =
                make_uint2(pk0, pk1);
        }
    __syncthreads();                           // B6 (pem/peb visible)

    // ---- relation + partial logits (K-half = sub), swapped MFMA ----
    {
        const bf16x8_t bz = {0, 0, 0, 0, 0, 0, 0, 0};
        f32x4_t lacc = {0.f, 0.f, 0.f, 0.f};
        #pragma unroll
        for (int kk = 0; kk < 4; ++kk) {
            int cb8 = (sub * 4 + kk) * 32 + quad * 8;
            uint4 pm4 = *(const uint4*)&bufR[R0 + ln15][cb8];
            uint4 pb4 = *(const uint4*)&bufP[R0 + ln15][cb8];
            uint4 q4  = qpre[kk];
            union { uint4 u; bf16x8_t v; } rr;
            rr.u.x = relpair(kpre[kk].x, q4.x, pm4.x, pb4.x);
            rr.u.y = relpair(kpre[kk].y, q4.y, pm4.y, pb4.y);
            rr.u.z = relpair(kpre[kk].z, q4.z, pm4.z, pb4.z);
            rr.u.w = relpair(kpre[kk].w, q4.w, pm4.w, pb4.w);
            bf16x8_t wfr = bz;
            if (ln15 < 8) wfr = *(const bf16x8_t*)(we1TF + ln15 * 256 + cb8);
            lacc = __builtin_amdgcn_mfma_f32_16x16x32_bf16(wfr, rr.v, lacc, 0, 0, 0);
        }
        // D[g = quad*4+r][s = ln15]: rows g<8 valid -> quad<2 stores float4
        if (quad < 2)
            *(f32x4_t*)&usP[sub][R0 + ln15][quad * 4] = lacc;
    }
    __syncthreads();                           // B7 (partials visible)

    // ---- combine + BN/relu + logits2 (even wave, lanes<16 = s) ----
    if (sub == 0 && lane < 16) {
        int s = lane;
        float uv[8], l[8];
        #pragma unroll
        for (int g = 0; g < 8; ++g) {
            float x = usP[0][R0 + s][g] + usP[1][R0 + s][g];
            uv[g] = fmaxf(x * swe8[g] + dwe8[g], 0.f);
        }
        #pragma unroll
        for (int g = 0; g < 8; ++g) {
            float x = web2[g];
            for (int gp = 0; gp < 8; ++gp) x += uv[gp] * we2s[gp][g];
            l[g] = x;
        }
        #pragma unroll
        for (int g = 0; g < 8; ++g) us_[R0 + s][g] = l[g];
    }
    WSYNC();

    // ---- softmax over s (even wave, lanes<8 = g) ----
    if (sub == 0 && lane < 8) {
        int g = lane;
        float mx = -1e30f;
        for (int s = 0; s < 16; ++s) mx = fmaxf(mx, us_[R0 + s][g]);
        float e[16], sum = 0.f;
        for (int s = 0; s < 16; ++s) { e[s] = __expf(us_[R0 + s][g] - mx); sum += e[s]; }
        float inv = 1.f / sum;
        for (int s = 0; s < 16; ++s) us_[R0 + s][g] = e[s] * inv;
    }
    __syncthreads();                           // B8 (softmax visible)

    // ---- output: wave pair = 128 lanes, 2 cols each ----
    {
        int idx2 = sub * 64 + lane;
        int c5 = idx2 * 2, g = c5 >> 5;
        float a0 = 0.f, a1 = 0.f;
        #pragma unroll
        for (int s = 0; s < 16; ++s) {
            int rv = rowg_[R0 + s];
            float wv_ = us_[R0 + s][g];
            unsigned int v2 = *(const unsigned int*)(vm + (size_t)rv * 256 + c5);
            unsigned int p2 = *(const unsigned int*)&bufP[R0 + s][c5];
            a0 += wv_ * (blo(v2) + blo(p2));
            a1 += wv_ * (bhi(v2) + bhi(p2));
        }
        *(float2*)(out + (size_t)Pg * 256 + c5) = make_float2(a0, a1);
    }
}

// ---------------------------------------------------------------------------
extern "C" void kernel_launch(void* const* d_in, const int* in_sizes, int n_in,
                              void* d_out, int out_size, void* d_ws, size_t ws_size,
                              hipStream_t stream)
{
    const float* feats  = (const float*)d_in[0];
    const float* coords = (const float*)d_in[1];
    const int*   index  = (const int*)d_in[2];
    const float* wq     = (const float*)d_in[3];
    const float* bq     = (const float*)d_in[4];
    const float* bnq    = (const float*)d_in[5];
    const float* wk     = (const float*)d_in[6];
    const float* bk     = (const float*)d_in[7];
    const float* bnk    = (const float*)d_in[8];
    const float* wv     = (const float*)d_in[9];
    const float* bv     = (const float*)d_in[10];
    const float* pm_w1  = (const float*)d_in[11];
    const float* pm_b1  = (const float*)d_in[12];
    const float* pm_bn  = (const float*)d_in[13];
    const float* pm_w2  = (const float*)d_in[14];
    const float* pm_b2  = (const float*)d_in[15];
    const float* pb_w1  = (const float*)d_in[16];
    const float* pb_b1  = (const float*)d_in[17];
    const float* pb_bn  = (const float*)d_in[18];
    const float* pb_w2  = (const float*)d_in[19];
    const float* pb_b2  = (const float*)d_in[20];
    const float* we_w1  = (const float*)d_in[21];
    const float* we_b1  = (const float*)d_in[22];
    const float* we_bn  = (const float*)d_in[23];
    const float* we_w2  = (const float*)d_in[24];
    const float* we_b2  = (const float*)d_in[25];

    unsigned short* qkv   = (unsigned short*)d_ws;
    unsigned short* wsT   = qkv + (size_t)3 * 8192 * 256;
    unsigned short* we1TF = wsT + 5 * 65536;
    unsigned short* w1F   = we1TF + 2048;
    float*          SS    = (float*)(w1F + 16384);

    const size_t need = (size_t)13281280;
    if (ws_size < need) {
        hipMemsetAsync(d_out, 0, (size_t)out_size * 4, stream);
        return;
    }

    k_prep<<<162,  256, 0, stream>>>(wq, wk, wv, pm_w2, pb_w2,
                                     pm_w1, pm_b1, pm_bn,
                                     pb_w1, pb_b1, pb_bn,
                                     we_w1,
                                     bq, bnq, bk, bnk, bv,
                                     wsT, w1F, we1TF, SS);
    k_qkv <<<768,  256, 0, stream>>>(feats, wsT, SS, qkv);
    k_main<<<2048, 512, 0, stream>>>(coords, index,
                                     qkv,
                                     qkv + (size_t)8192 * 256,
                                     qkv + (size_t)2 * 8192 * 256,
                                     wsT + 3 * 65536,
                                     wsT + 4 * 65536,
                                     w1F, we1TF,
                                     pm_b2, pb_b2,
                                     we_b1, we_bn, we_w2, we_b2,
                                     (float*)d_out);
}

// Round 7
// 206.302 us; speedup vs baseline: 1.3051x; 1.0292x over previous
//
#include <hip/hip_runtime.h>
#include <hip/hip_bf16.h>

// GroupedVectorSA (gfx950) — ROUND 19: R15 GEMM structure (78us best) +
// decoupled per-wave tail done with register discipline (R16 retry):
// full-K relation per wave, k/q/pm/pb loaded JIT (unroll 2, no hoisted
// prefetch arrays), no vpre, rowg via shfl. Drops usP + 2 barriers.
// k_prep/k_qkv: R16/R18 direct-store versions.

typedef __attribute__((ext_vector_type(8))) short bf16x8_t;
typedef __attribute__((ext_vector_type(4))) float f32x4_t;

#define BN_EPS 1e-5f
#define WSYNC() asm volatile("s_waitcnt lgkmcnt(0)" ::: "memory")

__device__ __forceinline__ float blo(unsigned int v) {
    union { unsigned int u; float f; } x; x.u = v << 16; return x.f;
}
__device__ __forceinline__ float bhi(unsigned int v) {
    union { unsigned int u; float f; } x; x.u = v & 0xffff0000u; return x.f;
}
__device__ __forceinline__ unsigned int fbits(float f) {
    union { float f; unsigned int u; } x; x.f = f; return x.u;
}
__device__ __forceinline__ unsigned short f2b(float f) {      // RNE fp32->bf16
    unsigned int u = fbits(f);
    return (unsigned short)((u + 0x7fffu + ((u >> 16) & 1u)) >> 16);
}
__device__ __forceinline__ float b2f(unsigned short h) {      // bf16->fp32 exact
    union { unsigned int u; float f; } x; x.u = ((unsigned int)h) << 16; return x.f;
}
__device__ __forceinline__ unsigned int f2bpk(float a, float b) {  // hw packed cvt
    union { __hip_bfloat162 h; unsigned int u; } x;
    x.h = __float22bfloat162_rn(make_float2(a, b));
    return x.u;
}
__device__ __forceinline__ unsigned int relpair(unsigned int kb, unsigned int qb,
                                                unsigned int pm_, unsigned int pb_) {
    float r0 = (blo(kb) - blo(qb)) * blo(pm_) + blo(pb_);
    float r1 = (bhi(kb) - bhi(qb)) * bhi(pm_) + bhi(pb_);
    return f2bpk(r0, r1);
}

// ---------------------------------------------------------------------------
// K0: blocks 0..159: 5 weights -> bf16 fragment-linear. 160: W1 frags.
//     161: we1TF + qkv scale/shift fold.
// ---------------------------------------------------------------------------
__global__ __launch_bounds__(256) void k_prep(
    const float* __restrict__ wq, const float* __restrict__ wk,
    const float* __restrict__ wv, const float* __restrict__ pm2,
    const float* __restrict__ pb2,
    const float* __restrict__ pm_w1, const float* __restrict__ pm_b1,
    const float* __restrict__ pm_bn,
    const float* __restrict__ pb_w1, const float* __restrict__ pb_b1,
    const float* __restrict__ pb_bn,
    const float* __restrict__ we_w1,
    const float* __restrict__ bq, const float* __restrict__ bnq,
    const float* __restrict__ bk, const float* __restrict__ bnk,
    const float* __restrict__ bv,
    unsigned short* __restrict__ wsT, unsigned short* __restrict__ w1F,
    unsigned short* __restrict__ we1TF, float* __restrict__ SS)
{
    const int bid = blockIdx.x, t = threadIdx.x;
    if (bid < 160) {
        __shared__ unsigned short T[32][72];
        const int mat = bid >> 5;
        const int kk  = (bid >> 2) & 7;
        const int ntq = bid & 3;
        const float* s = (mat == 0) ? wq : (mat == 1) ? wk : (mat == 2) ? wv
                         : (mat == 3) ? pm2 : pb2;
        {
            int c = t & 63, r0 = t >> 6;
            for (int i = 0; i < 8; ++i) {
                int r = r0 + i * 4;
                T[r][c] = f2b(s[(kk * 32 + r) * 256 + ntq * 64 + c]);
            }
        }
        __syncthreads();
        {
            int seg = t >> 6, lane = t & 63;
            int col = seg * 16 + (lane & 15);
            int kr  = (lane >> 4) * 8;
            unsigned int v[8];
            #pragma unroll
            for (int j = 0; j < 8; ++j) v[j] = T[kr + j][col];
            uint4 o;
            o.x = v[0] | (v[1] << 16);
            o.y = v[2] | (v[3] << 16);
            o.z = v[4] | (v[5] << 16);
            o.w = v[6] | (v[7] << 16);
            *(uint4*)(wsT + mat * 65536 + (ntq * 4 + seg) * 4096 + kk * 512 + lane * 8) = o;
        }
    } else if (bid == 160) {
        // Build W1 B-fragments (K-slot packed, BN folded), pass0=pm, pass1=pb.
        int c = t;                      // column 0..255
        int nt = c >> 4, l15 = c & 15;
        float sm = pm_bn[c] / sqrtf(pm_bn[768 + c] + BN_EPS);
        float sb = pb_bn[c] / sqrtf(pb_bn[768 + c] + BN_EPS);
        float W[2][4];
        W[0][0] = pm_w1[c] * sm; W[0][1] = pm_w1[256 + c] * sm;
        W[0][2] = pm_w1[512 + c] * sm;
        W[0][3] = (pm_b1[c] - pm_bn[512 + c]) * sm + pm_bn[256 + c];
        W[1][0] = pb_w1[c] * sb; W[1][1] = pb_w1[256 + c] * sb;
        W[1][2] = pb_w1[512 + c] * sb;
        W[1][3] = (pb_b1[c] - pb_bn[512 + c]) * sb + pb_bn[256 + c];
        for (int pass = 0; pass < 2; ++pass) {
            unsigned short xh = f2b(W[pass][0]), xl = f2b(W[pass][0] - b2f(xh));
            unsigned short yh = f2b(W[pass][1]), yl = f2b(W[pass][1] - b2f(yh));
            unsigned short zh = f2b(W[pass][2]), zl = f2b(W[pass][2] - b2f(zh));
            unsigned short bh = f2b(W[pass][3]), bl = f2b(W[pass][3] - b2f(bh));
            unsigned short sl[16] = { xh, xh, xl, yh, yh, yl, zh, zh, zl,
                                      bh, bl, 0, 0, 0, 0, 0 };
            for (int q = 0; q < 4; ++q)
                for (int j = 0; j < 8; ++j)
                    w1F[((pass * 16 + nt) * 64 + q * 16 + l15) * 8 + j] =
                        (q < 2) ? sl[q * 8 + j] : (unsigned short)0;
        }
    } else {
        for (int j = 0; j < 8; ++j) {
            int e = t * 8 + j;
            int g = e >> 8, c = e & 255;
            we1TF[g * 256 + c] = f2b(we_w1[c * 8 + g]);
        }
        // qkv epilogue scale/shift fold: y = raw*sc + sh (relu for q,k)
        int c = t;
        float sq = bnq[c] / sqrtf(bnq[768 + c] + BN_EPS);
        SS[c]        = sq;
        SS[256 + c]  = (bq[c] - bnq[512 + c]) * sq + bnq[256 + c];
        float sk = bnk[c] / sqrtf(bnk[768 + c] + BN_EPS);
        SS[512 + c]  = sk;
        SS[768 + c]  = (bk[c] - bnk[512 + c]) * sk + bnk[256 + c];
        SS[1024 + c] = 1.0f;
        SS[1280 + c] = bv[c];
    }
}

// ---------------------------------------------------------------------------
// K1: q/k/v GEMM, operand-swapped -> direct reg->global store, one barrier.
// grid=768, blk=256.
// ---------------------------------------------------------------------------
__global__ __launch_bounds__(256) void k_qkv(
    const float* __restrict__ feats,
    const unsigned short* __restrict__ wT,
    const float* __restrict__ SS,
    unsigned short* __restrict__ qkv)
{
    __shared__ unsigned short A[32][264];
    const int t    = threadIdx.x;
    const int widx = blockIdx.x >> 8;
    const int mb   = blockIdx.x & 255;

    for (int i = 0; i < 8; ++i) {
        int row = 4 * i + (t >> 6), col = (t & 63) * 4;
        float4 f = *(const float4*)(feats + (mb * 32 + row) * 256 + col);
        *(uint2*)&A[row][col] = make_uint2(f2bpk(f.x, f.y), f2bpk(f.z, f.w));
    }
    __syncthreads();

    const int lane = t & 63, w = t >> 6;
    const int ln15 = lane & 15, quad = lane >> 4;
    const int mt = w & 1, nh = w >> 1;

    bf16x8_t afr[8];
    #pragma unroll
    for (int kk = 0; kk < 8; ++kk)
        afr[kk] = *(const bf16x8_t*)&A[mt * 16 + ln15][kk * 32 + quad * 8];

    const unsigned short* W = wT + widx * 65536;
    unsigned short* dst = qkv + (size_t)widx * 8192 * 256;

    f32x4_t acc[8];
    for (int j = 0; j < 8; ++j) acc[j] = (f32x4_t){0.f, 0.f, 0.f, 0.f};

    #pragma unroll
    for (int kk = 0; kk < 8; ++kk) {
        #pragma unroll
        for (int j = 0; j < 8; ++j) {
            int nt = nh * 8 + j;
            bf16x8_t wfr = *(const bf16x8_t*)(W + ((nt * 8 + kk) * 64 + lane) * 8);
            acc[j] = __builtin_amdgcn_mfma_f32_16x16x32_bf16(wfr, afr[kk], acc[j], 0, 0, 0);
        }
    }

    // D^T: lane holds channels n0..n0+3 (rows), point m = mt*16+ln15 (col).
    const float* S = SS + widx * 512;
    const int row = mb * 32 + mt * 16 + ln15;
    #pragma unroll
    for (int j = 0; j < 8; ++j) {
        int n0 = (nh * 8 + j) * 16 + quad * 4;
        float4 s4 = *(const float4*)(S + n0);
        float4 h4 = *(const float4*)(S + 256 + n0);
        float y0 = acc[j][0] * s4.x + h4.x;
        float y1 = acc[j][1] * s4.y + h4.y;
        float y2 = acc[j][2] * s4.z + h4.z;
        float y3 = acc[j][3] * s4.w + h4.w;
        if (widx < 2) {
            y0 = fmaxf(y0, 0.f); y1 = fmaxf(y1, 0.f);
            y2 = fmaxf(y2, 0.f); y3 = fmaxf(y3, 0.f);
        }
        *(uint2*)(dst + (size_t)row * 256 + n0) =
            make_uint2(f2bpk(y0, y1), f2bpk(y2, y3));
    }
}

// ---------------------------------------------------------------------------
// K2: fused main. 512 threads (8 waves), 4 points/block, wave pair per point.
// grid=2048. B1..B6 as R15; relation full-K per wave (JIT loads, unroll 2);
// per-wave tail (no usP/B7/B8). LDS ~76.4KB -> 2 blocks/CU.
// ---------------------------------------------------------------------------
__global__ __launch_bounds__(512, 4) void k_main(
    const float* __restrict__ coords,
    const int*   __restrict__ index,
    const unsigned short* __restrict__ qm,
    const unsigned short* __restrict__ km,
    const unsigned short* __restrict__ vm,
    const unsigned short* __restrict__ pmw2F,
    const unsigned short* __restrict__ pbw2F,
    const unsigned short* __restrict__ w1F,
    const unsigned short* __restrict__ we1TF,
    const float* __restrict__ pm_b2, const float* __restrict__ pb_b2,
    const float* __restrict__ we_b1, const float* __restrict__ we_bn,
    const float* __restrict__ we_w2, const float* __restrict__ we_b2,
    float* __restrict__ out)
{
    __shared__ unsigned short bufR[64][264];   // h_pb -> h_pm -> pem
    __shared__ unsigned short bufP[64][264];   // peb
    __shared__ unsigned short posX[64][32];    // B-operand K-slots (hi/lo packed)
    __shared__ float us_[8][16][12];           // per-wave logits (stride 12)
    __shared__ float we2s[8][8];
    __shared__ float web2[8], swe8[8], dwe8[8];

    const int t   = threadIdx.x;
    const int P0  = blockIdx.x * 4;
    const int bb_ = P0 >> 12;
    const int w = t >> 6, lane = t & 63;
    const int ln15 = lane & 15, quad = lane >> 4;
    const int p   = w >> 1, sub = w & 1;       // wave pair (2p, 2p+1) owns point p
    const int R0  = p * 16;
    const int Pg  = P0 + p;

    // ---- per-lane neighbor row (s=ln15) ----
    const int rg = (bb_ << 12) + index[Pg * 16 + ln15];

    // ---- stage posX K-slots (t<64 -> row m=t) + small consts ----
    if (t < 64) {
        int m  = t;
        int Pr = P0 + (m >> 4);
        int rs = (bb_ << 12) + index[Pr * 16 + (m & 15)];
        float x = coords[Pr * 3 + 0] - coords[rs * 3 + 0];
        float y = coords[Pr * 3 + 1] - coords[rs * 3 + 1];
        float z = coords[Pr * 3 + 2] - coords[rs * 3 + 2];
        unsigned short xh = f2b(x), xl = f2b(x - b2f(xh));
        unsigned short yh = f2b(y), yl = f2b(y - b2f(yh));
        unsigned short zh = f2b(z), zl = f2b(z - b2f(zh));
        const unsigned short one = 0x3f80;
        posX[m][0] = xh; posX[m][1] = xl; posX[m][2] = xh;
        posX[m][3] = yh; posX[m][4] = yl; posX[m][5] = yh;
        posX[m][6] = zh; posX[m][7] = zl; posX[m][8] = zh;
        posX[m][9] = one; posX[m][10] = one;
        #pragma unroll
        for (int j2 = 11; j2 < 32; ++j2) posX[m][j2] = 0;
        we2s[m >> 3][m & 7] = we_w2[m];
    }
    if (t < 8) {
        float s = we_bn[t] / sqrtf(we_bn[24 + t] + BN_EPS);
        swe8[t] = s;
        dwe8[t] = (we_b1[t] - we_bn[16 + t]) * s + we_bn[8 + t];
        web2[t] = we_b2[t];
    }
    __syncthreads();                           // B1 (posX visible)

    // ---- pos fragments (B-operand of swapped h-MFMAs, held in regs) ----
    bf16x8_t afrP[4];
    #pragma unroll
    for (int mt = 0; mt < 4; ++mt)
        afrP[mt] = *(const bf16x8_t*)&posX[mt * 16 + ln15][quad * 8];

    // ---- h_pb = relu(pos @ W1pb) via swapped MFMA -> bufR (b64 writes) ----
    {
        f32x4_t hb[2][4];
        for (int ntl = 0; ntl < 2; ++ntl)
            for (int mt = 0; mt < 4; ++mt) hb[ntl][mt] = (f32x4_t){0.f, 0.f, 0.f, 0.f};
        #pragma unroll
        for (int ntl = 0; ntl < 2; ++ntl) {
            int nt = w * 2 + ntl;
            bf16x8_t wfr = *(const bf16x8_t*)(w1F + ((16 + nt) * 64 + lane) * 8);
            #pragma unroll
            for (int mt = 0; mt < 4; ++mt)
                hb[ntl][mt] = __builtin_amdgcn_mfma_f32_16x16x32_bf16(wfr, afrP[mt], hb[ntl][mt], 0, 0, 0);
        }
        #pragma unroll
        for (int ntl = 0; ntl < 2; ++ntl) {
            int cb = w * 32 + ntl * 16 + quad * 4;
            #pragma unroll
            for (int mt = 0; mt < 4; ++mt) {
                unsigned int pk0 = f2bpk(fmaxf(hb[ntl][mt][0], 0.f), fmaxf(hb[ntl][mt][1], 0.f));
                unsigned int pk1 = f2bpk(fmaxf(hb[ntl][mt][2], 0.f), fmaxf(hb[ntl][mt][3], 0.f));
                *(uint2*)&bufR[mt * 16 + ln15][cb] = make_uint2(pk0, pk1);
            }
        }
    }
    __syncthreads();                           // B2 (h_pb visible)

    // ---- phase: peb MFMA (w2pb^T x h) + h_pm MFMA (W1pm^T x pos, held) ----
    f32x4_t accM[2][4];                        // h_pm accumulators (held past B3)
    for (int ntl = 0; ntl < 2; ++ntl)
        for (int mt = 0; mt < 4; ++mt) accM[ntl][mt] = (f32x4_t){0.f, 0.f, 0.f, 0.f};
    #pragma unroll
    for (int ntl = 0; ntl < 2; ++ntl) {
        int nt = w * 2 + ntl;
        bf16x8_t wfr = *(const bf16x8_t*)(w1F + (nt * 64 + lane) * 8);
        #pragma unroll
        for (int mt = 0; mt < 4; ++mt)
            accM[ntl][mt] = __builtin_amdgcn_mfma_f32_16x16x32_bf16(wfr, afrP[mt], accM[ntl][mt], 0, 0, 0);
    }
    f32x4_t acc[2][4];
    {
        f32x4_t b0 = *(const f32x4_t*)(pb_b2 + (w * 2    ) * 16 + quad * 4);
        f32x4_t b1 = *(const f32x4_t*)(pb_b2 + (w * 2 + 1) * 16 + quad * 4);
        for (int mt = 0; mt < 4; ++mt) { acc[0][mt] = b0; acc[1][mt] = b1; }
    }
    #pragma unroll
    for (int kk = 0; kk < 8; ++kk) {
        bf16x8_t afr[4];
        #pragma unroll
        for (int mt = 0; mt < 4; ++mt)
            afr[mt] = *(const bf16x8_t*)&bufR[mt * 16 + ln15][kk * 32 + quad * 8];
        #pragma unroll
        for (int ntl = 0; ntl < 2; ++ntl) {
            int nt = w * 2 + ntl;
            bf16x8_t wfr = *(const bf16x8_t*)(pbw2F + ((nt * 8 + kk) * 64 + lane) * 8);
            #pragma unroll
            for (int mt = 0; mt < 4; ++mt)
                acc[ntl][mt] = __builtin_amdgcn_mfma_f32_16x16x32_bf16(wfr, afr[mt], acc[ntl][mt], 0, 0, 0);
        }
    }
    // peb epilogue -> bufP (free buffer, no barrier needed before write)
    #pragma unroll
    for (int ntl = 0; ntl < 2; ++ntl) {
        int cb = w * 32 + ntl * 16 + quad * 4;
        #pragma unroll
        for (int mt = 0; mt < 4; ++mt) {
            unsigned int pk0 = f2bpk(acc[ntl][mt][0], acc[ntl][mt][1]);
            unsigned int pk1 = f2bpk(acc[ntl][mt][2], acc[ntl][mt][3]);
            *(uint2*)&bufP[mt * 16 + ln15][cb] = make_uint2(pk0, pk1);
        }
    }
    __syncthreads();                           // B3 (bufR h_pb reads done)

    // ---- h_pm epilogue (relu+pack) -> bufR ----
    #pragma unroll
    for (int ntl = 0; ntl < 2; ++ntl) {
        int cb = w * 32 + ntl * 16 + quad * 4;
        #pragma unroll
        for (int mt = 0; mt < 4; ++mt) {
            unsigned int pk0 = f2bpk(fmaxf(accM[ntl][mt][0], 0.f), fmaxf(accM[ntl][mt][1], 0.f));
            unsigned int pk1 = f2bpk(fmaxf(accM[ntl][mt][2], 0.f), fmaxf(accM[ntl][mt][3], 0.f));
            *(uint2*)&bufR[mt * 16 + ln15][cb] = make_uint2(pk0, pk1);
        }
    }
    __syncthreads();                           // B4 (h_pm visible)

    // ---- pem MFMA (w2pm^T x h) ----
    {
        f32x4_t b0 = *(const f32x4_t*)(pm_b2 + (w * 2    ) * 16 + quad * 4);
        f32x4_t b1 = *(const f32x4_t*)(pm_b2 + (w * 2 + 1) * 16 + quad * 4);
        for (int mt = 0; mt < 4; ++mt) { acc[0][mt] = b0; acc[1][mt] = b1; }
    }
    #pragma unroll
    for (int kk = 0; kk < 8; ++kk) {
        bf16x8_t afr[4];
        #pragma unroll
        for (int mt = 0; mt < 4; ++mt)
            afr[mt] = *(const bf16x8_t*)&bufR[mt * 16 + ln15][kk * 32 + quad * 8];
        #pragma unroll
        for (int ntl = 0; ntl < 2; ++ntl) {
            int nt = w * 2 + ntl;
            bf16x8_t wfr = *(const bf16x8_t*)(pmw2F + ((nt * 8 + kk) * 64 + lane) * 8);
            #pragma unroll
            for (int mt = 0; mt < 4; ++mt)
                acc[ntl][mt] = __builtin_amdgcn_mfma_f32_16x16x32_bf16(wfr, afr[mt], acc[ntl][mt], 0, 0, 0);
        }
    }
    __syncthreads();                           // B5 (bufR h_pm reads done)

    // pem epilogue -> bufR
    #pragma unroll
    for (int ntl = 0; ntl < 2; ++ntl) {
        int cb = w * 32 + ntl * 16 + quad * 4;
        #pragma unroll
        for (int mt = 0; mt < 4; ++mt) {
            unsigned int pk0 = f2bpk(acc[ntl][mt][0], acc[ntl][mt][1]);
            unsigned int pk1 = f2bpk(acc[ntl][mt][2], acc[ntl][mt][3]);
            *(uint2*)&bufR[mt * 16 + ln15][cb] = make_uint2(pk0, pk1);
        }
    }
    __syncthreads();                           // B6 (pem/peb visible) — LAST barrier

    // ---- relation + logits (FULL K per wave), JIT loads, swapped MFMA ----
    {
        const bf16x8_t bz = {0, 0, 0, 0, 0, 0, 0, 0};
        f32x4_t lacc = {0.f, 0.f, 0.f, 0.f};
        #pragma unroll 2
        for (int kk = 0; kk < 8; ++kk) {
            int cb8 = kk * 32 + quad * 8;
            uint4 k4  = *(const uint4*)(km + (size_t)rg * 256 + cb8);
            uint4 q4  = *(const uint4*)(qm + (size_t)Pg * 256 + cb8);
            uint4 pm4 = *(const uint4*)&bufR[R0 + ln15][cb8];
            uint4 pb4 = *(const uint4*)&bufP[R0 + ln15][cb8];
            union { uint4 u; bf16x8_t v; } rr;
            rr.u.x = relpair(k4.x, q4.x, pm4.x, pb4.x);
            rr.u.y = relpair(k4.y, q4.y, pm4.y, pb4.y);
            rr.u.z = relpair(k4.z, q4.z, pm4.z, pb4.z);
            rr.u.w = relpair(k4.w, q4.w, pm4.w, pb4.w);
            bf16x8_t wfr = bz;
            if (ln15 < 8) wfr = *(const bf16x8_t*)(we1TF + ln15 * 256 + cb8);
            lacc = __builtin_amdgcn_mfma_f32_16x16x32_bf16(wfr, rr.v, lacc, 0, 0, 0);
        }
        // D[g=quad*4+r][s=ln15], rows g<8 valid -> quad<2. BN+relu in-reg.
        if (quad < 2) {
            f32x4_t uv4;
            #pragma unroll
            for (int r = 0; r < 4; ++r) {
                int g = quad * 4 + r;
                uv4[r] = fmaxf(lacc[r] * swe8[g] + dwe8[g], 0.f);
            }
            *(f32x4_t*)&us_[w][ln15][quad * 4] = uv4;
        }
    }
    WSYNC();

    // ---- logits2 (per wave, lanes<16 = s) ----
    if (lane < 16) {
        int s = lane;
        float uvv[8], l[8];
        #pragma unroll
        for (int g = 0; g < 8; ++g) uvv[g] = us_[w][s][g];
        #pragma unroll
        for (int g = 0; g < 8; ++g) {
            float x = web2[g];
            #pragma unroll
            for (int gp = 0; gp < 8; ++gp) x += uvv[gp] * we2s[gp][g];
            l[g] = x;
        }
        #pragma unroll
        for (int g = 0; g < 8; ++g) us_[w][s][g] = l[g];
    }
    WSYNC();

    // ---- softmax over s (per wave, lanes<8 = g) ----
    if (lane < 8) {
        int g = lane;
        float mx = -1e30f;
        for (int s = 0; s < 16; ++s) mx = fmaxf(mx, us_[w][s][g]);
        float e[16], sum = 0.f;
        for (int s = 0; s < 16; ++s) { e[s] = __expf(us_[w][s][g] - mx); sum += e[s]; }
        float inv = 1.f / sum;
        for (int s = 0; s < 16; ++s) us_[w][s][g] = e[s] * inv;
    }
    WSYNC();

    // ---- output: wave handles cols sub*128 .. sub*128+127 (2 per lane) ----
    {
        int c2 = sub * 128 + lane * 2;
        int g = c2 >> 5;
        float a0 = 0.f, a1 = 0.f;
        #pragma unroll
        for (int s = 0; s < 16; ++s) {
            int rv = __shfl(rg, s);
            float wv_ = us_[w][s][g];
            unsigned int v2 = *(const unsigned int*)(vm + (size_t)rv * 256 + c2);
            unsigned int p2 = *(const unsigned int*)&bufP[R0 + s][c2];
            a0 += wv_ * (blo(v2) + blo(p2));
            a1 += wv_ * (bhi(v2) + bhi(p2));
        }
        *(float2*)(out + (size_t)Pg * 256 + c2) = make_float2(a0, a1);
    }
}

// ---------------------------------------------------------------------------
extern "C" void kernel_launch(void* const* d_in, const int* in_sizes, int n_in,
                              void* d_out, int out_size, void* d_ws, size_t ws_size,
                              hipStream_t stream)
{
    const float* feats  = (const float*)d_in[0];
    const float* coords = (const float*)d_in[1];
    const int*   index  = (const int*)d_in[2];
    const float* wq     = (const float*)d_in[3];
    const float* bq     = (const float*)d_in[4];
    const float* bnq    = (const float*)d_in[5];
    const float* wk     = (const float*)d_in[6];
    const float* bk     = (const float*)d_in[7];
    const float* bnk    = (const float*)d_in[8];
    const float* wv     = (const float*)d_in[9];
    const float* bv     = (const float*)d_in[10];
    const float* pm_w1  = (const float*)d_in[11];
    const float* pm_b1  = (const float*)d_in[12];
    const float* pm_bn  = (const float*)d_in[13];
    const float* pm_w2  = (const float*)d_in[14];
    const float* pm_b2  = (const float*)d_in[15];
    const float* pb_w1  = (const float*)d_in[16];
    const float* pb_b1  = (const float*)d_in[17];
    const float* pb_bn  = (const float*)d_in[18];
    const float* pb_w2  = (const float*)d_in[19];
    const float* pb_b2  = (const float*)d_in[20];
    const float* we_w1  = (const float*)d_in[21];
    const float* we_b1  = (const float*)d_in[22];
    const float* we_bn  = (const float*)d_in[23];
    const float* we_w2  = (const float*)d_in[24];
    const float* we_b2  = (const float*)d_in[25];

    unsigned short* qkv   = (unsigned short*)d_ws;
    unsigned short* wsT   = qkv + (size_t)3 * 8192 * 256;
    unsigned short* we1TF = wsT + 5 * 65536;
    unsigned short* w1F   = we1TF + 2048;
    float*          SS    = (float*)(w1F + 16384);

    const size_t need = (size_t)13281280;
    if (ws_size < need) {
        hipMemsetAsync(d_out, 0, (size_t)out_size * 4, stream);
        return;
    }

    k_prep<<<162,  256, 0, stream>>>(wq, wk, wv, pm_w2, pb_w2,
                                     pm_w1, pm_b1, pm_bn,
                                     pb_w1, pb_b1, pb_bn,
                                     we_w1,
                                     bq, bnq, bk, bnk, bv,
                                     wsT, w1F, we1TF, SS);
    k_qkv <<<768,  256, 0, stream>>>(feats, wsT, SS, qkv);
    k_main<<<2048, 512, 0, stream>>>(coords, index,
                                     qkv,
                                     qkv + (size_t)8192 * 256,
                                     qkv + (size_t)2 * 8192 * 256,
                                     wsT + 3 * 65536,
                                     wsT + 4 * 65536,
                                     w1F, we1TF,
                                     pm_b2, pb_b2,
                                     we_b1, we_bn, we_w2, we_b2,
                                     (float*)d_out);
}

// Round 10
// 185.867 us; speedup vs baseline: 1.4485x; 1.1099x over previous
//
#include <hip/hip_runtime.h>
#include <hip/hip_bf16.h>

// GroupedVectorSA (gfx950) — ROUND 21: exact R15 k_main structure (78us
// verified, all 8 barriers, sub==0 tail) + ONE safe addition: vpre[16]
// v-gather prefetch in the post-relation dead-register window (race-free:
// reads constant global memory only). R20's per-wave tail retired (raced).
// k_prep/k_qkv: direct-store versions (verified correct in R18/R19 runs).

typedef __attribute__((ext_vector_type(8))) short bf16x8_t;
typedef __attribute__((ext_vector_type(4))) float f32x4_t;

#define BN_EPS 1e-5f
#define WSYNC() asm volatile("s_waitcnt lgkmcnt(0)" ::: "memory")

__device__ __forceinline__ float blo(unsigned int v) {
    union { unsigned int u; float f; } x; x.u = v << 16; return x.f;
}
__device__ __forceinline__ float bhi(unsigned int v) {
    union { unsigned int u; float f; } x; x.u = v & 0xffff0000u; return x.f;
}
__device__ __forceinline__ unsigned int fbits(float f) {
    union { float f; unsigned int u; } x; x.f = f; return x.u;
}
__device__ __forceinline__ unsigned short f2b(float f) {      // RNE fp32->bf16
    unsigned int u = fbits(f);
    return (unsigned short)((u + 0x7fffu + ((u >> 16) & 1u)) >> 16);
}
__device__ __forceinline__ float b2f(unsigned short h) {      // bf16->fp32 exact
    union { unsigned int u; float f; } x; x.u = ((unsigned int)h) << 16; return x.f;
}
__device__ __forceinline__ unsigned int f2bpk(float a, float b) {  // hw packed cvt
    union { __hip_bfloat162 h; unsigned int u; } x;
    x.h = __float22bfloat162_rn(make_float2(a, b));
    return x.u;
}
__device__ __forceinline__ unsigned int relpair(unsigned int kb, unsigned int qb,
                                                unsigned int pm_, unsigned int pb_) {
    float r0 = (blo(kb) - blo(qb)) * blo(pm_) + blo(pb_);
    float r1 = (bhi(kb) - bhi(qb)) * bhi(pm_) + bhi(pb_);
    return f2bpk(r0, r1);
}

// ---------------------------------------------------------------------------
// K0: blocks 0..159: 5 weights -> bf16 fragment-linear. 160: W1 frags.
//     161: we1TF + qkv scale/shift fold.
// ---------------------------------------------------------------------------
__global__ __launch_bounds__(256) void k_prep(
    const float* __restrict__ wq, const float* __restrict__ wk,
    const float* __restrict__ wv, const float* __restrict__ pm2,
    const float* __restrict__ pb2,
    const float* __restrict__ pm_w1, const float* __restrict__ pm_b1,
    const float* __restrict__ pm_bn,
    const float* __restrict__ pb_w1, const float* __restrict__ pb_b1,
    const float* __restrict__ pb_bn,
    const float* __restrict__ we_w1,
    const float* __restrict__ bq, const float* __restrict__ bnq,
    const float* __restrict__ bk, const float* __restrict__ bnk,
    const float* __restrict__ bv,
    unsigned short* __restrict__ wsT, unsigned short* __restrict__ w1F,
    unsigned short* __restrict__ we1TF, float* __restrict__ SS)
{
    const int bid = blockIdx.x, t = threadIdx.x;
    if (bid < 160) {
        __shared__ unsigned short T[32][72];
        const int mat = bid >> 5;
        const int kk  = (bid >> 2) & 7;
        const int ntq = bid & 3;
        const float* s = (mat == 0) ? wq : (mat == 1) ? wk : (mat == 2) ? wv
                         : (mat == 3) ? pm2 : pb2;
        {
            int c = t & 63, r0 = t >> 6;
            for (int i = 0; i < 8; ++i) {
                int r = r0 + i * 4;
                T[r][c] = f2b(s[(kk * 32 + r) * 256 + ntq * 64 + c]);
            }
        }
        __syncthreads();
        {
            int seg = t >> 6, lane = t & 63;
            int col = seg * 16 + (lane & 15);
            int kr  = (lane >> 4) * 8;
            unsigned int v[8];
            #pragma unroll
            for (int j = 0; j < 8; ++j) v[j] = T[kr + j][col];
            uint4 o;
            o.x = v[0] | (v[1] << 16);
            o.y = v[2] | (v[3] << 16);
            o.z = v[4] | (v[5] << 16);
            o.w = v[6] | (v[7] << 16);
            *(uint4*)(wsT + mat * 65536 + (ntq * 4 + seg) * 4096 + kk * 512 + lane * 8) = o;
        }
    } else if (bid == 160) {
        // Build W1 B-fragments (K-slot packed, BN folded), pass0=pm, pass1=pb.
        int c = t;                      // column 0..255
        int nt = c >> 4, l15 = c & 15;
        float sm = pm_bn[c] / sqrtf(pm_bn[768 + c] + BN_EPS);
        float sb = pb_bn[c] / sqrtf(pb_bn[768 + c] + BN_EPS);
        float W[2][4];
        W[0][0] = pm_w1[c] * sm; W[0][1] = pm_w1[256 + c] * sm;
        W[0][2] = pm_w1[512 + c] * sm;
        W[0][3] = (pm_b1[c] - pm_bn[512 + c]) * sm + pm_bn[256 + c];
        W[1][0] = pb_w1[c] * sb; W[1][1] = pb_w1[256 + c] * sb;
        W[1][2] = pb_w1[512 + c] * sb;
        W[1][3] = (pb_b1[c] - pb_bn[512 + c]) * sb + pb_bn[256 + c];
        for (int pass = 0; pass < 2; ++pass) {
            unsigned short xh = f2b(W[pass][0]), xl = f2b(W[pass][0] - b2f(xh));
            unsigned short yh = f2b(W[pass][1]), yl = f2b(W[pass][1] - b2f(yh));
            unsigned short zh = f2b(W[pass][2]), zl = f2b(W[pass][2] - b2f(zh));
            unsigned short bh = f2b(W[pass][3]), bl = f2b(W[pass][3] - b2f(bh));
            unsigned short sl[16] = { xh, xh, xl, yh, yh, yl, zh, zh, zl,
                                      bh, bl, 0, 0, 0, 0, 0 };
            for (int q = 0; q < 4; ++q)
                for (int j = 0; j < 8; ++j)
                    w1F[((pass * 16 + nt) * 64 + q * 16 + l15) * 8 + j] =
                        (q < 2) ? sl[q * 8 + j] : (unsigned short)0;
        }
    } else {
        for (int j = 0; j < 8; ++j) {
            int e = t * 8 + j;
            int g = e >> 8, c = e & 255;
            we1TF[g * 256 + c] = f2b(we_w1[c * 8 + g]);
        }
        // qkv epilogue scale/shift fold: y = raw*sc + sh (relu for q,k)
        int c = t;
        float sq = bnq[c] / sqrtf(bnq[768 + c] + BN_EPS);
        SS[c]        = sq;
        SS[256 + c]  = (bq[c] - bnq[512 + c]) * sq + bnq[256 + c];
        float sk = bnk[c] / sqrtf(bnk[768 + c] + BN_EPS);
        SS[512 + c]  = sk;
        SS[768 + c]  = (bk[c] - bnk[512 + c]) * sk + bnk[256 + c];
        SS[1024 + c] = 1.0f;
        SS[1280 + c] = bv[c];
    }
}

// ---------------------------------------------------------------------------
// K1: q/k/v GEMM, operand-swapped -> direct reg->global store, one barrier.
// grid=768, blk=256.
// ---------------------------------------------------------------------------
__global__ __launch_bounds__(256) void k_qkv(
    const float* __restrict__ feats,
    const unsigned short* __restrict__ wT,
    const float* __restrict__ SS,
    unsigned short* __restrict__ qkv)
{
    __shared__ unsigned short A[32][264];
    const int t    = threadIdx.x;
    const int widx = blockIdx.x >> 8;
    const int mb   = blockIdx.x & 255;

    for (int i = 0; i < 8; ++i) {
        int row = 4 * i + (t >> 6), col = (t & 63) * 4;
        float4 f = *(const float4*)(feats + (mb * 32 + row) * 256 + col);
        *(uint2*)&A[row][col] = make_uint2(f2bpk(f.x, f.y), f2bpk(f.z, f.w));
    }
    __syncthreads();

    const int lane = t & 63, w = t >> 6;
    const int ln15 = lane & 15, quad = lane >> 4;
    const int mt = w & 1, nh = w >> 1;

    bf16x8_t afr[8];
    #pragma unroll
    for (int kk = 0; kk < 8; ++kk)
        afr[kk] = *(const bf16x8_t*)&A[mt * 16 + ln15][kk * 32 + quad * 8];

    const unsigned short* W = wT + widx * 65536;
    unsigned short* dst = qkv + (size_t)widx * 8192 * 256;

    f32x4_t acc[8];
    for (int j = 0; j < 8; ++j) acc[j] = (f32x4_t){0.f, 0.f, 0.f, 0.f};

    #pragma unroll
    for (int kk = 0; kk < 8; ++kk) {
        #pragma unroll
        for (int j = 0; j < 8; ++j) {
            int nt = nh * 8 + j;
            bf16x8_t wfr = *(const bf16x8_t*)(W + ((nt * 8 + kk) * 64 + lane) * 8);
            acc[j] = __builtin_amdgcn_mfma_f32_16x16x32_bf16(wfr, afr[kk], acc[j], 0, 0, 0);
        }
    }

    // D^T: lane holds channels n0..n0+3 (rows), point m = mt*16+ln15 (col).
    const float* S = SS + widx * 512;
    const int row = mb * 32 + mt * 16 + ln15;
    #pragma unroll
    for (int j = 0; j < 8; ++j) {
        int n0 = (nh * 8 + j) * 16 + quad * 4;
        float4 s4 = *(const float4*)(S + n0);
        float4 h4 = *(const float4*)(S + 256 + n0);
        float y0 = acc[j][0] * s4.x + h4.x;
        float y1 = acc[j][1] * s4.y + h4.y;
        float y2 = acc[j][2] * s4.z + h4.z;
        float y3 = acc[j][3] * s4.w + h4.w;
        if (widx < 2) {
            y0 = fmaxf(y0, 0.f); y1 = fmaxf(y1, 0.f);
            y2 = fmaxf(y2, 0.f); y3 = fmaxf(y3, 0.f);
        }
        *(uint2*)(dst + (size_t)row * 256 + n0) =
            make_uint2(f2bpk(y0, y1), f2bpk(y2, y3));
    }
}

// ---------------------------------------------------------------------------
// K2: fused main. 512 threads (8 waves), 4 points/block, wave pair per point.
// grid=2048. Exact R15 structure (8 barriers, sub==0 tail) + vpre[16].
// LDS ~78.4KB -> 2 blocks/CU.
// ---------------------------------------------------------------------------
__global__ __launch_bounds__(512, 4) void k_main(
    const float* __restrict__ coords,
    const int*   __restrict__ index,
    const unsigned short* __restrict__ qm,
    const unsigned short* __restrict__ km,
    const unsigned short* __restrict__ vm,
    const unsigned short* __restrict__ pmw2F,
    const unsigned short* __restrict__ pbw2F,
    const unsigned short* __restrict__ w1F,
    const unsigned short* __restrict__ we1TF,
    const float* __restrict__ pm_b2, const float* __restrict__ pb_b2,
    const float* __restrict__ we_b1, const float* __restrict__ we_bn,
    const float* __restrict__ we_w2, const float* __restrict__ we_b2,
    float* __restrict__ out)
{
    __shared__ unsigned short bufR[64][264];   // h_pb -> h_pm -> pem
    __shared__ unsigned short bufP[64][264];   // peb
    __shared__ unsigned short posX[64][32];    // B-operand K-slots (hi/lo packed)
    __shared__ float usP[2][64][8];            // partial logits (K-split halves)
    __shared__ float us_[64][8];               // logits -> softmax w (shared)
    __shared__ int   rowg_[64];
    __shared__ float we2s[8][8];
    __shared__ float web2[8], swe8[8], dwe8[8];

    const int t   = threadIdx.x;
    const int P0  = blockIdx.x * 4;
    const int bb_ = P0 >> 12;
    const int w = t >> 6, lane = t & 63;
    const int ln15 = lane & 15, quad = lane >> 4;
    const int p   = w >> 1, sub = w & 1;       // wave pair (2p, 2p+1) owns point p
    const int R0  = p * 16;
    const int Pg  = P0 + p;

    // ---- per-lane neighbor row (s=ln15) ----
    const int rg = (bb_ << 12) + index[Pg * 16 + ln15];

    // ---- stage posX K-slots (t<64 -> row m=t) + small consts ----
    if (t < 64) {
        int m  = t;
        int Pr = P0 + (m >> 4);
        int rs = (bb_ << 12) + index[Pr * 16 + (m & 15)];
        rowg_[m] = rs;
        float x = coords[Pr * 3 + 0] - coords[rs * 3 + 0];
        float y = coords[Pr * 3 + 1] - coords[rs * 3 + 1];
        float z = coords[Pr * 3 + 2] - coords[rs * 3 + 2];
        unsigned short xh = f2b(x), xl = f2b(x - b2f(xh));
        unsigned short yh = f2b(y), yl = f2b(y - b2f(yh));
        unsigned short zh = f2b(z), zl = f2b(z - b2f(zh));
        const unsigned short one = 0x3f80;
        posX[m][0] = xh; posX[m][1] = xl; posX[m][2] = xh;
        posX[m][3] = yh; posX[m][4] = yl; posX[m][5] = yh;
        posX[m][6] = zh; posX[m][7] = zl; posX[m][8] = zh;
        posX[m][9] = one; posX[m][10] = one;
        #pragma unroll
        for (int j2 = 11; j2 < 32; ++j2) posX[m][j2] = 0;
        we2s[m >> 3][m & 7] = we_w2[m];
    }
    if (t < 8) {
        float s = we_bn[t] / sqrtf(we_bn[24 + t] + BN_EPS);
        swe8[t] = s;
        dwe8[t] = (we_b1[t] - we_bn[16 + t]) * s + we_bn[8 + t];
        web2[t] = we_b2[t];
    }
    __syncthreads();                           // B1 (posX visible)

    // ---- pos fragments (B-operand of swapped h-MFMAs, held in regs) ----
    bf16x8_t afrP[4];
    #pragma unroll
    for (int mt = 0; mt < 4; ++mt)
        afrP[mt] = *(const bf16x8_t*)&posX[mt * 16 + ln15][quad * 8];

    // ---- h_pb = relu(pos @ W1pb) via swapped MFMA -> bufR (b64 writes) ----
    {
        f32x4_t hb[2][4];
        for (int ntl = 0; ntl < 2; ++ntl)
            for (int mt = 0; mt < 4; ++mt) hb[ntl][mt] = (f32x4_t){0.f, 0.f, 0.f, 0.f};
        #pragma unroll
        for (int ntl = 0; ntl < 2; ++ntl) {
            int nt = w * 2 + ntl;
            bf16x8_t wfr = *(const bf16x8_t*)(w1F + ((16 + nt) * 64 + lane) * 8);
            #pragma unroll
            for (int mt = 0; mt < 4; ++mt)
                hb[ntl][mt] = __builtin_amdgcn_mfma_f32_16x16x32_bf16(wfr, afrP[mt], hb[ntl][mt], 0, 0, 0);
        }
        #pragma unroll
        for (int ntl = 0; ntl < 2; ++ntl) {
            int cb = w * 32 + ntl * 16 + quad * 4;
            #pragma unroll
            for (int mt = 0; mt < 4; ++mt) {
                unsigned int pk0 = f2bpk(fmaxf(hb[ntl][mt][0], 0.f), fmaxf(hb[ntl][mt][1], 0.f));
                unsigned int pk1 = f2bpk(fmaxf(hb[ntl][mt][2], 0.f), fmaxf(hb[ntl][mt][3], 0.f));
                *(uint2*)&bufR[mt * 16 + ln15][cb] = make_uint2(pk0, pk1);
            }
        }
    }
    __syncthreads();                           // B2 (h_pb visible)

    // ---- phase: peb MFMA (w2pb^T x h) + h_pm MFMA (W1pm^T x pos, held) ----
    f32x4_t accM[2][4];                        // h_pm accumulators (held past B3)
    for (int ntl = 0; ntl < 2; ++ntl)
        for (int mt = 0; mt < 4; ++mt) accM[ntl][mt] = (f32x4_t){0.f, 0.f, 0.f, 0.f};
    #pragma unroll
    for (int ntl = 0; ntl < 2; ++ntl) {
        int nt = w * 2 + ntl;
        bf16x8_t wfr = *(const bf16x8_t*)(w1F + (nt * 64 + lane) * 8);
        #pragma unroll
        for (int mt = 0; mt < 4; ++mt)
            accM[ntl][mt] = __builtin_amdgcn_mfma_f32_16x16x32_bf16(wfr, afrP[mt], accM[ntl][mt], 0, 0, 0);
    }
    f32x4_t acc[2][4];
    {
        f32x4_t b0 = *(const f32x4_t*)(pb_b2 + (w * 2    ) * 16 + quad * 4);
        f32x4_t b1 = *(const f32x4_t*)(pb_b2 + (w * 2 + 1) * 16 + quad * 4);
        for (int mt = 0; mt < 4; ++mt) { acc[0][mt] = b0; acc[1][mt] = b1; }
    }
    #pragma unroll
    for (int kk = 0; kk < 8; ++kk) {
        bf16x8_t afr[4];
        #pragma unroll
        for (int mt = 0; mt < 4; ++mt)
            afr[mt] = *(const bf16x8_t*)&bufR[mt * 16 + ln15][kk * 32 + quad * 8];
        #pragma unroll
        for (int ntl = 0; ntl < 2; ++ntl) {
            int nt = w * 2 + ntl;
            bf16x8_t wfr = *(const bf16x8_t*)(pbw2F + ((nt * 8 + kk) * 64 + lane) * 8);
            #pragma unroll
            for (int mt = 0; mt < 4; ++mt)
                acc[ntl][mt] = __builtin_amdgcn_mfma_f32_16x16x32_bf16(wfr, afr[mt], acc[ntl][mt], 0, 0, 0);
        }
    }
    // peb epilogue -> bufP (free buffer, no barrier needed before write)
    #pragma unroll
    for (int ntl = 0; ntl < 2; ++ntl) {
        int cb = w * 32 + ntl * 16 + quad * 4;
        #pragma unroll
        for (int mt = 0; mt < 4; ++mt) {
            unsigned int pk0 = f2bpk(acc[ntl][mt][0], acc[ntl][mt][1]);
            unsigned int pk1 = f2bpk(acc[ntl][mt][2], acc[ntl][mt][3]);
            *(uint2*)&bufP[mt * 16 + ln15][cb] = make_uint2(pk0, pk1);
        }
    }
    __syncthreads();                           // B3 (bufR h_pb reads done)

    // ---- h_pm epilogue (relu+pack) -> bufR ----
    #pragma unroll
    for (int ntl = 0; ntl < 2; ++ntl) {
        int cb = w * 32 + ntl * 16 + quad * 4;
        #pragma unroll
        for (int mt = 0; mt < 4; ++mt) {
            unsigned int pk0 = f2bpk(fmaxf(accM[ntl][mt][0], 0.f), fmaxf(accM[ntl][mt][1], 0.f));
            unsigned int pk1 = f2bpk(fmaxf(accM[ntl][mt][2], 0.f), fmaxf(accM[ntl][mt][3], 0.f));
            *(uint2*)&bufR[mt * 16 + ln15][cb] = make_uint2(pk0, pk1);
        }
    }
    __syncthreads();                           // B4 (h_pm visible)

    // ---- pem MFMA (w2pm^T x h) + k-gather prefetch (K-half = sub) ----
    uint4 kpre[4];
    #pragma unroll
    for (int kk = 0; kk < 4; ++kk)
        kpre[kk] = *(const uint4*)(km + (size_t)rg * 256 + (sub * 4 + kk) * 32 + quad * 8);
    {
        f32x4_t b0 = *(const f32x4_t*)(pm_b2 + (w * 2    ) * 16 + quad * 4);
        f32x4_t b1 = *(const f32x4_t*)(pm_b2 + (w * 2 + 1) * 16 + quad * 4);
        for (int mt = 0; mt < 4; ++mt) { acc[0][mt] = b0; acc[1][mt] = b1; }
    }
    #pragma unroll
    for (int kk = 0; kk < 8; ++kk) {
        bf16x8_t afr[4];
        #pragma unroll
        for (int mt = 0; mt < 4; ++mt)
            afr[mt] = *(const bf16x8_t*)&bufR[mt * 16 + ln15][kk * 32 + quad * 8];
        #pragma unroll
        for (int ntl = 0; ntl < 2; ++ntl) {
            int nt = w * 2 + ntl;
            bf16x8_t wfr = *(const bf16x8_t*)(pmw2F + ((nt * 8 + kk) * 64 + lane) * 8);
            #pragma unroll
            for (int mt = 0; mt < 4; ++mt)
                acc[ntl][mt] = __builtin_amdgcn_mfma_f32_16x16x32_bf16(wfr, afr[mt], acc[ntl][mt], 0, 0, 0);
        }
    }
    __syncthreads();                           // B5 (bufR h_pm reads done)

    // ---- q prefetch (K-half) ----
    uint4 qpre[4];
    #pragma unroll
    for (int kk = 0; kk < 4; ++kk)
        qpre[kk] = *(const uint4*)(qm + (size_t)Pg * 256 + (sub * 4 + kk) * 32 + quad * 8);

    // pem epilogue -> bufR
    #pragma unroll
    for (int ntl = 0; ntl < 2; ++ntl) {
        int cb = w * 32 + ntl * 16 + quad * 4;
        #pragma unroll
        for (int mt = 0; mt < 4; ++mt) {
            unsigned int pk0 = f2bpk(acc[ntl][mt][0], acc[ntl][mt][1]);
            unsigned int pk1 = f2bpk(acc[ntl][mt][2], acc[ntl][mt][3]);
            *(uint2*)&bufR[mt * 16 + ln15][cb] = make_uint2(pk0, pk1);
        }
    }
    __syncthreads();                           // B6 (pem/peb visible)

    // ---- relation + partial logits (K-half = sub), swapped MFMA ----
    {
        const bf16x8_t bz = {0, 0, 0, 0, 0, 0, 0, 0};
        f32x4_t lacc = {0.f, 0.f, 0.f, 0.f};
        #pragma unroll
        for (int kk = 0; kk < 4; ++kk) {
            int cb8 = (sub * 4 + kk) * 32 + quad * 8;
            uint4 pm4 = *(const uint4*)&bufR[R0 + ln15][cb8];
            uint4 pb4 = *(const uint4*)&bufP[R0 + ln15][cb8];
            uint4 q4  = qpre[kk];
            union { uint4 u; bf16x8_t v; } rr;
            rr.u.x = relpair(kpre[kk].x, q4.x, pm4.x, pb4.x);
            rr.u.y = relpair(kpre[kk].y, q4.y, pm4.y, pb4.y);
            rr.u.z = relpair(kpre[kk].z, q4.z, pm4.z, pb4.z);
            rr.u.w = relpair(kpre[kk].w, q4.w, pm4.w, pb4.w);
            bf16x8_t wfr = bz;
            if (ln15 < 8) wfr = *(const bf16x8_t*)(we1TF + ln15 * 256 + cb8);
            lacc = __builtin_amdgcn_mfma_f32_16x16x32_bf16(wfr, rr.v, lacc, 0, 0, 0);
        }
        // D[g = quad*4+r][s = ln15]: rows g<8 valid -> quad<2 stores float4
        if (quad < 2)
            *(f32x4_t*)&usP[sub][R0 + ln15][quad * 4] = lacc;
    }

    // ---- v-gather prefetch (acc/accM/afrP/kpre/qpre dead; 16 VGPRs) ----
    const int c5 = (sub * 64 + lane) * 2;      // output cols (2 per lane)
    unsigned int vpre[16];
    #pragma unroll
    for (int s = 0; s < 16; ++s) {
        int rv = rowg_[R0 + s];
        vpre[s] = *(const unsigned int*)(vm + (size_t)rv * 256 + c5);
    }
    __syncthreads();                           // B7 (partials visible)

    // ---- combine + BN/relu + logits2 (even wave, lanes<16 = s) ----
    if (sub == 0 && lane < 16) {
        int s = lane;
        float uv[8], l[8];
        #pragma unroll
        for (int g = 0; g < 8; ++g) {
            float x = usP[0][R0 + s][g] + usP[1][R0 + s][g];
            uv[g] = fmaxf(x * swe8[g] + dwe8[g], 0.f);
        }
        #pragma unroll
        for (int g = 0; g < 8; ++g) {
            float x = web2[g];
            #pragma unroll
            for (int gp = 0; gp < 8; ++gp) x += uv[gp] * we2s[gp][g];
            l[g] = x;
        }
        #pragma unroll
        for (int g = 0; g < 8; ++g) us_[R0 + s][g] = l[g];
    }
    WSYNC();

    // ---- softmax over s (even wave, lanes<8 = g) ----
    if (sub == 0 && lane < 8) {
        int g = lane;
        float mx = -1e30f;
        for (int s = 0; s < 16; ++s) mx = fmaxf(mx, us_[R0 + s][g]);
        float e[16], sum = 0.f;
        for (int s = 0; s < 16; ++s) { e[s] = __expf(us_[R0 + s][g] - mx); sum += e[s]; }
        float inv = 1.f / sum;
        for (int s = 0; s < 16; ++s) us_[R0 + s][g] = e[s] * inv;
    }
    __syncthreads();                           // B8 (softmax visible)

    // ---- output: wave pair = 128 lanes, 2 cols each ----
    {
        int g = c5 >> 5;
        float a0 = 0.f, a1 = 0.f;
        #pragma unroll
        for (int s = 0; s < 16; ++s) {
            float wv_ = us_[R0 + s][g];
            unsigned int v2 = vpre[s];
            unsigned int p2 = *(const unsigned int*)&bufP[R0 + s][c5];
            a0 += wv_ * (blo(v2) + blo(p2));
            a1 += wv_ * (bhi(v2) + bhi(p2));
        }
        *(float2*)(out + (size_t)Pg * 256 + c5) = make_float2(a0, a1);
    }
}

// ---------------------------------------------------------------------------
extern "C" void kernel_launch(void* const* d_in, const int* in_sizes, int n_in,
                              void* d_out, int out_size, void* d_ws, size_t ws_size,
                              hipStream_t stream)
{
    const float* feats  = (const float*)d_in[0];
    const float* coords = (const float*)d_in[1];
    const int*   index  = (const int*)d_in[2];
    const float* wq     = (const float*)d_in[3];
    const float* bq     = (const float*)d_in[4];
    const float* bnq    = (const float*)d_in[5];
    const float* wk     = (const float*)d_in[6];
    const float* bk     = (const float*)d_in[7];
    const float* bnk    = (const float*)d_in[8];
    const float* wv     = (const float*)d_in[9];
    const float* bv     = (const float*)d_in[10];
    const float* pm_w1  = (const float*)d_in[11];
    const float* pm_b1  = (const float*)d_in[12];
    const float* pm_bn  = (const float*)d_in[13];
    const float* pm_w2  = (const float*)d_in[14];
    const float* pm_b2  = (const float*)d_in[15];
    const float* pb_w1  = (const float*)d_in[16];
    const float* pb_b1  = (const float*)d_in[17];
    const float* pb_bn  = (const float*)d_in[18];
    const float* pb_w2  = (const float*)d_in[19];
    const float* pb_b2  = (const float*)d_in[20];
    const float* we_w1  = (const float*)d_in[21];
    const float* we_b1  = (const float*)d_in[22];
    const float* we_bn  = (const float*)d_in[23];
    const float* we_w2  = (const float*)d_in[24];
    const float* we_b2  = (const float*)d_in[25];

    unsigned short* qkv   = (unsigned short*)d_ws;
    unsigned short* wsT   = qkv + (size_t)3 * 8192 * 256;
    unsigned short* we1TF = wsT + 5 * 65536;
    unsigned short* w1F   = we1TF + 2048;
    float*          SS    = (float*)(w1F + 16384);

    const size_t need = (size_t)13281280;
    if (ws_size < need) {
        hipMemsetAsync(d_out, 0, (size_t)out_size * 4, stream);
        return;
    }

    k_prep<<<162,  256, 0, stream>>>(wq, wk, wv, pm_w2, pb_w2,
                                     pm_w1, pm_b1, pm_bn,
                                     pb_w1, pb_b1, pb_bn,
                                     we_w1,
                                     bq, bnq, bk, bnk, bv,
                                     wsT, w1F, we1TF, SS);
    k_qkv <<<768,  256, 0, stream>>>(feats, wsT, SS, qkv);
    k_main<<<2048, 512, 0, stream>>>(coords, index,
                                     qkv,
                                     qkv + (size_t)8192 * 256,
                                     qkv + (size_t)2 * 8192 * 256,
                                     wsT + 3 * 65536,
                                     wsT + 4 * 65536,
                                     w1F, we1TF,
                                     pm_b2, pb_b2,
                                     we_b1, we_bn, we_w2, we_b2,
                                     (float*)d_out);
}

// Round 11
// 185.660 us; speedup vs baseline: 1.4502x; 1.0011x over previous
//
#include <hip/hip_runtime.h>
#include <hip/hip_bf16.h>

// GroupedVectorSA (gfx950) — ROUND 22: R21 (73.6us verified) +
// (1) wave-parallel tail: combine on 64 lanes (shfl_xor uv exchange),
//     softmax on 64 lanes (shfl reductions). SAME sub==0 gating and B7/B8
//     barriers as verified R15/R21 — only within-wave compute reorganized.
// (2) s_setprio(1) around peb/pem MFMA clusters (T5, cross-block diversity).
// us_ padded [64][10] (+512B LDS, still 2 blocks/CU).

typedef __attribute__((ext_vector_type(8))) short bf16x8_t;
typedef __attribute__((ext_vector_type(4))) float f32x4_t;

#define BN_EPS 1e-5f
#define WSYNC() asm volatile("s_waitcnt lgkmcnt(0)" ::: "memory")

__device__ __forceinline__ float blo(unsigned int v) {
    union { unsigned int u; float f; } x; x.u = v << 16; return x.f;
}
__device__ __forceinline__ float bhi(unsigned int v) {
    union { unsigned int u; float f; } x; x.u = v & 0xffff0000u; return x.f;
}
__device__ __forceinline__ unsigned int fbits(float f) {
    union { float f; unsigned int u; } x; x.f = f; return x.u;
}
__device__ __forceinline__ unsigned short f2b(float f) {      // RNE fp32->bf16
    unsigned int u = fbits(f);
    return (unsigned short)((u + 0x7fffu + ((u >> 16) & 1u)) >> 16);
}
__device__ __forceinline__ float b2f(unsigned short h) {      // bf16->fp32 exact
    union { unsigned int u; float f; } x; x.u = ((unsigned int)h) << 16; return x.f;
}
__device__ __forceinline__ unsigned int f2bpk(float a, float b) {  // hw packed cvt
    union { __hip_bfloat162 h; unsigned int u; } x;
    x.h = __float22bfloat162_rn(make_float2(a, b));
    return x.u;
}
__device__ __forceinline__ unsigned int relpair(unsigned int kb, unsigned int qb,
                                                unsigned int pm_, unsigned int pb_) {
    float r0 = (blo(kb) - blo(qb)) * blo(pm_) + blo(pb_);
    float r1 = (bhi(kb) - bhi(qb)) * bhi(pm_) + bhi(pb_);
    return f2bpk(r0, r1);
}

// ---------------------------------------------------------------------------
// K0: blocks 0..159: 5 weights -> bf16 fragment-linear. 160: W1 frags.
//     161: we1TF + qkv scale/shift fold.
// ---------------------------------------------------------------------------
__global__ __launch_bounds__(256) void k_prep(
    const float* __restrict__ wq, const float* __restrict__ wk,
    const float* __restrict__ wv, const float* __restrict__ pm2,
    const float* __restrict__ pb2,
    const float* __restrict__ pm_w1, const float* __restrict__ pm_b1,
    const float* __restrict__ pm_bn,
    const float* __restrict__ pb_w1, const float* __restrict__ pb_b1,
    const float* __restrict__ pb_bn,
    const float* __restrict__ we_w1,
    const float* __restrict__ bq, const float* __restrict__ bnq,
    const float* __restrict__ bk, const float* __restrict__ bnk,
    const float* __restrict__ bv,
    unsigned short* __restrict__ wsT, unsigned short* __restrict__ w1F,
    unsigned short* __restrict__ we1TF, float* __restrict__ SS)
{
    const int bid = blockIdx.x, t = threadIdx.x;
    if (bid < 160) {
        __shared__ unsigned short T[32][72];
        const int mat = bid >> 5;
        const int kk  = (bid >> 2) & 7;
        const int ntq = bid & 3;
        const float* s = (mat == 0) ? wq : (mat == 1) ? wk : (mat == 2) ? wv
                         : (mat == 3) ? pm2 : pb2;
        {
            int c = t & 63, r0 = t >> 6;
            for (int i = 0; i < 8; ++i) {
                int r = r0 + i * 4;
                T[r][c] = f2b(s[(kk * 32 + r) * 256 + ntq * 64 + c]);
            }
        }
        __syncthreads();
        {
            int seg = t >> 6, lane = t & 63;
            int col = seg * 16 + (lane & 15);
            int kr  = (lane >> 4) * 8;
            unsigned int v[8];
            #pragma unroll
            for (int j = 0; j < 8; ++j) v[j] = T[kr + j][col];
            uint4 o;
            o.x = v[0] | (v[1] << 16);
            o.y = v[2] | (v[3] << 16);
            o.z = v[4] | (v[5] << 16);
            o.w = v[6] | (v[7] << 16);
            *(uint4*)(wsT + mat * 65536 + (ntq * 4 + seg) * 4096 + kk * 512 + lane * 8) = o;
        }
    } else if (bid == 160) {
        // Build W1 B-fragments (K-slot packed, BN folded), pass0=pm, pass1=pb.
        int c = t;                      // column 0..255
        int nt = c >> 4, l15 = c & 15;
        float sm = pm_bn[c] / sqrtf(pm_bn[768 + c] + BN_EPS);
        float sb = pb_bn[c] / sqrtf(pb_bn[768 + c] + BN_EPS);
        float W[2][4];
        W[0][0] = pm_w1[c] * sm; W[0][1] = pm_w1[256 + c] * sm;
        W[0][2] = pm_w1[512 + c] * sm;
        W[0][3] = (pm_b1[c] - pm_bn[512 + c]) * sm + pm_bn[256 + c];
        W[1][0] = pb_w1[c] * sb; W[1][1] = pb_w1[256 + c] * sb;
        W[1][2] = pb_w1[512 + c] * sb;
        W[1][3] = (pb_b1[c] - pb_bn[512 + c]) * sb + pb_bn[256 + c];
        for (int pass = 0; pass < 2; ++pass) {
            unsigned short xh = f2b(W[pass][0]), xl = f2b(W[pass][0] - b2f(xh));
            unsigned short yh = f2b(W[pass][1]), yl = f2b(W[pass][1] - b2f(yh));
            unsigned short zh = f2b(W[pass][2]), zl = f2b(W[pass][2] - b2f(zh));
            unsigned short bh = f2b(W[pass][3]), bl = f2b(W[pass][3] - b2f(bh));
            unsigned short sl[16] = { xh, xh, xl, yh, yh, yl, zh, zh, zl,
                                      bh, bl, 0, 0, 0, 0, 0 };
            for (int q = 0; q < 4; ++q)
                for (int j = 0; j < 8; ++j)
                    w1F[((pass * 16 + nt) * 64 + q * 16 + l15) * 8 + j] =
                        (q < 2) ? sl[q * 8 + j] : (unsigned short)0;
        }
    } else {
        for (int j = 0; j < 8; ++j) {
            int e = t * 8 + j;
            int g = e >> 8, c = e & 255;
            we1TF[g * 256 + c] = f2b(we_w1[c * 8 + g]);
        }
        // qkv epilogue scale/shift fold: y = raw*sc + sh (relu for q,k)
        int c = t;
        float sq = bnq[c] / sqrtf(bnq[768 + c] + BN_EPS);
        SS[c]        = sq;
        SS[256 + c]  = (bq[c] - bnq[512 + c]) * sq + bnq[256 + c];
        float sk = bnk[c] / sqrtf(bnk[768 + c] + BN_EPS);
        SS[512 + c]  = sk;
        SS[768 + c]  = (bk[c] - bnk[512 + c]) * sk + bnk[256 + c];
        SS[1024 + c] = 1.0f;
        SS[1280 + c] = bv[c];
    }
}

// ---------------------------------------------------------------------------
// K1: q/k/v GEMM, operand-swapped -> direct reg->global store, one barrier.
// grid=768, blk=256.
// ---------------------------------------------------------------------------
__global__ __launch_bounds__(256) void k_qkv(
    const float* __restrict__ feats,
    const unsigned short* __restrict__ wT,
    const float* __restrict__ SS,
    unsigned short* __restrict__ qkv)
{
    __shared__ unsigned short A[32][264];
    const int t    = threadIdx.x;
    const int widx = blockIdx.x >> 8;
    const int mb   = blockIdx.x & 255;

    for (int i = 0; i < 8; ++i) {
        int row = 4 * i + (t >> 6), col = (t & 63) * 4;
        float4 f = *(const float4*)(feats + (mb * 32 + row) * 256 + col);
        *(uint2*)&A[row][col] = make_uint2(f2bpk(f.x, f.y), f2bpk(f.z, f.w));
    }
    __syncthreads();

    const int lane = t & 63, w = t >> 6;
    const int ln15 = lane & 15, quad = lane >> 4;
    const int mt = w & 1, nh = w >> 1;

    bf16x8_t afr[8];
    #pragma unroll
    for (int kk = 0; kk < 8; ++kk)
        afr[kk] = *(const bf16x8_t*)&A[mt * 16 + ln15][kk * 32 + quad * 8];

    const unsigned short* W = wT + widx * 65536;
    unsigned short* dst = qkv + (size_t)widx * 8192 * 256;

    f32x4_t acc[8];
    for (int j = 0; j < 8; ++j) acc[j] = (f32x4_t){0.f, 0.f, 0.f, 0.f};

    #pragma unroll
    for (int kk = 0; kk < 8; ++kk) {
        #pragma unroll
        for (int j = 0; j < 8; ++j) {
            int nt = nh * 8 + j;
            bf16x8_t wfr = *(const bf16x8_t*)(W + ((nt * 8 + kk) * 64 + lane) * 8);
            acc[j] = __builtin_amdgcn_mfma_f32_16x16x32_bf16(wfr, afr[kk], acc[j], 0, 0, 0);
        }
    }

    // D^T: lane holds channels n0..n0+3 (rows), point m = mt*16+ln15 (col).
    const float* S = SS + widx * 512;
    const int row = mb * 32 + mt * 16 + ln15;
    #pragma unroll
    for (int j = 0; j < 8; ++j) {
        int n0 = (nh * 8 + j) * 16 + quad * 4;
        float4 s4 = *(const float4*)(S + n0);
        float4 h4 = *(const float4*)(S + 256 + n0);
        float y0 = acc[j][0] * s4.x + h4.x;
        float y1 = acc[j][1] * s4.y + h4.y;
        float y2 = acc[j][2] * s4.z + h4.z;
        float y3 = acc[j][3] * s4.w + h4.w;
        if (widx < 2) {
            y0 = fmaxf(y0, 0.f); y1 = fmaxf(y1, 0.f);
            y2 = fmaxf(y2, 0.f); y3 = fmaxf(y3, 0.f);
        }
        *(uint2*)(dst + (size_t)row * 256 + n0) =
            make_uint2(f2bpk(y0, y1), f2bpk(y2, y3));
    }
}

// ---------------------------------------------------------------------------
// K2: fused main. 512 threads (8 waves), 4 points/block, wave pair per point.
// grid=2048. R21 structure (8 barriers) + wave-parallel tail + setprio.
// LDS ~79.4KB -> 2 blocks/CU.
// ---------------------------------------------------------------------------
__global__ __launch_bounds__(512, 4) void k_main(
    const float* __restrict__ coords,
    const int*   __restrict__ index,
    const unsigned short* __restrict__ qm,
    const unsigned short* __restrict__ km,
    const unsigned short* __restrict__ vm,
    const unsigned short* __restrict__ pmw2F,
    const unsigned short* __restrict__ pbw2F,
    const unsigned short* __restrict__ w1F,
    const unsigned short* __restrict__ we1TF,
    const float* __restrict__ pm_b2, const float* __restrict__ pb_b2,
    const float* __restrict__ we_b1, const float* __restrict__ we_bn,
    const float* __restrict__ we_w2, const float* __restrict__ we_b2,
    float* __restrict__ out)
{
    __shared__ unsigned short bufR[64][264];   // h_pb -> h_pm -> pem
    __shared__ unsigned short bufP[64][264];   // peb
    __shared__ unsigned short posX[64][32];    // B-operand K-slots (hi/lo packed)
    __shared__ float usP[2][64][8];            // partial logits (K-split halves)
    __shared__ float us_[64][10];              // logits -> softmax (pad stride 10)
    __shared__ int   rowg_[64];
    __shared__ float we2s[8][8];
    __shared__ float web2[8], swe8[8], dwe8[8];

    const int t   = threadIdx.x;
    const int P0  = blockIdx.x * 4;
    const int bb_ = P0 >> 12;
    const int w = t >> 6, lane = t & 63;
    const int ln15 = lane & 15, quad = lane >> 4;
    const int p   = w >> 1, sub = w & 1;       // wave pair (2p, 2p+1) owns point p
    const int R0  = p * 16;
    const int Pg  = P0 + p;

    // ---- per-lane neighbor row (s=ln15) ----
    const int rg = (bb_ << 12) + index[Pg * 16 + ln15];

    // ---- stage posX K-slots (t<64 -> row m=t) + small consts ----
    if (t < 64) {
        int m  = t;
        int Pr = P0 + (m >> 4);
        int rs = (bb_ << 12) + index[Pr * 16 + (m & 15)];
        rowg_[m] = rs;
        float x = coords[Pr * 3 + 0] - coords[rs * 3 + 0];
        float y = coords[Pr * 3 + 1] - coords[rs * 3 + 1];
        float z = coords[Pr * 3 + 2] - coords[rs * 3 + 2];
        unsigned short xh = f2b(x), xl = f2b(x - b2f(xh));
        unsigned short yh = f2b(y), yl = f2b(y - b2f(yh));
        unsigned short zh = f2b(z), zl = f2b(z - b2f(zh));
        const unsigned short one = 0x3f80;
        posX[m][0] = xh; posX[m][1] = xl; posX[m][2] = xh;
        posX[m][3] = yh; posX[m][4] = yl; posX[m][5] = yh;
        posX[m][6] = zh; posX[m][7] = zl; posX[m][8] = zh;
        posX[m][9] = one; posX[m][10] = one;
        #pragma unroll
        for (int j2 = 11; j2 < 32; ++j2) posX[m][j2] = 0;
        we2s[m >> 3][m & 7] = we_w2[m];
    }
    if (t < 8) {
        float s = we_bn[t] / sqrtf(we_bn[24 + t] + BN_EPS);
        swe8[t] = s;
        dwe8[t] = (we_b1[t] - we_bn[16 + t]) * s + we_bn[8 + t];
        web2[t] = we_b2[t];
    }
    __syncthreads();                           // B1 (posX visible)

    // ---- pos fragments (B-operand of swapped h-MFMAs, held in regs) ----
    bf16x8_t afrP[4];
    #pragma unroll
    for (int mt = 0; mt < 4; ++mt)
        afrP[mt] = *(const bf16x8_t*)&posX[mt * 16 + ln15][quad * 8];

    // ---- h_pb = relu(pos @ W1pb) via swapped MFMA -> bufR (b64 writes) ----
    {
        f32x4_t hb[2][4];
        for (int ntl = 0; ntl < 2; ++ntl)
            for (int mt = 0; mt < 4; ++mt) hb[ntl][mt] = (f32x4_t){0.f, 0.f, 0.f, 0.f};
        #pragma unroll
        for (int ntl = 0; ntl < 2; ++ntl) {
            int nt = w * 2 + ntl;
            bf16x8_t wfr = *(const bf16x8_t*)(w1F + ((16 + nt) * 64 + lane) * 8);
            #pragma unroll
            for (int mt = 0; mt < 4; ++mt)
                hb[ntl][mt] = __builtin_amdgcn_mfma_f32_16x16x32_bf16(wfr, afrP[mt], hb[ntl][mt], 0, 0, 0);
        }
        #pragma unroll
        for (int ntl = 0; ntl < 2; ++ntl) {
            int cb = w * 32 + ntl * 16 + quad * 4;
            #pragma unroll
            for (int mt = 0; mt < 4; ++mt) {
                unsigned int pk0 = f2bpk(fmaxf(hb[ntl][mt][0], 0.f), fmaxf(hb[ntl][mt][1], 0.f));
                unsigned int pk1 = f2bpk(fmaxf(hb[ntl][mt][2], 0.f), fmaxf(hb[ntl][mt][3], 0.f));
                *(uint2*)&bufR[mt * 16 + ln15][cb] = make_uint2(pk0, pk1);
            }
        }
    }
    __syncthreads();                           // B2 (h_pb visible)

    // ---- phase: peb MFMA (w2pb^T x h) + h_pm MFMA (W1pm^T x pos, held) ----
    f32x4_t accM[2][4];                        // h_pm accumulators (held past B3)
    for (int ntl = 0; ntl < 2; ++ntl)
        for (int mt = 0; mt < 4; ++mt) accM[ntl][mt] = (f32x4_t){0.f, 0.f, 0.f, 0.f};
    #pragma unroll
    for (int ntl = 0; ntl < 2; ++ntl) {
        int nt = w * 2 + ntl;
        bf16x8_t wfr = *(const bf16x8_t*)(w1F + (nt * 64 + lane) * 8);
        #pragma unroll
        for (int mt = 0; mt < 4; ++mt)
            accM[ntl][mt] = __builtin_amdgcn_mfma_f32_16x16x32_bf16(wfr, afrP[mt], accM[ntl][mt], 0, 0, 0);
    }
    f32x4_t acc[2][4];
    {
        f32x4_t b0 = *(const f32x4_t*)(pb_b2 + (w * 2    ) * 16 + quad * 4);
        f32x4_t b1 = *(const f32x4_t*)(pb_b2 + (w * 2 + 1) * 16 + quad * 4);
        for (int mt = 0; mt < 4; ++mt) { acc[0][mt] = b0; acc[1][mt] = b1; }
    }
    __builtin_amdgcn_s_setprio(1);
    #pragma unroll
    for (int kk = 0; kk < 8; ++kk) {
        bf16x8_t afr[4];
        #pragma unroll
        for (int mt = 0; mt < 4; ++mt)
            afr[mt] = *(const bf16x8_t*)&bufR[mt * 16 + ln15][kk * 32 + quad * 8];
        #pragma unroll
        for (int ntl = 0; ntl < 2; ++ntl) {
            int nt = w * 2 + ntl;
            bf16x8_t wfr = *(const bf16x8_t*)(pbw2F + ((nt * 8 + kk) * 64 + lane) * 8);
            #pragma unroll
            for (int mt = 0; mt < 4; ++mt)
                acc[ntl][mt] = __builtin_amdgcn_mfma_f32_16x16x32_bf16(wfr, afr[mt], acc[ntl][mt], 0, 0, 0);
        }
    }
    __builtin_amdgcn_s_setprio(0);
    // peb epilogue -> bufP (free buffer, no barrier needed before write)
    #pragma unroll
    for (int ntl = 0; ntl < 2; ++ntl) {
        int cb = w * 32 + ntl * 16 + quad * 4;
        #pragma unroll
        for (int mt = 0; mt < 4; ++mt) {
            unsigned int pk0 = f2bpk(acc[ntl][mt][0], acc[ntl][mt][1]);
            unsigned int pk1 = f2bpk(acc[ntl][mt][2], acc[ntl][mt][3]);
            *(uint2*)&bufP[mt * 16 + ln15][cb] = make_uint2(pk0, pk1);
        }
    }
    __syncthreads();                           // B3 (bufR h_pb reads done)

    // ---- h_pm epilogue (relu+pack) -> bufR ----
    #pragma unroll
    for (int ntl = 0; ntl < 2; ++ntl) {
        int cb = w * 32 + ntl * 16 + quad * 4;
        #pragma unroll
        for (int mt = 0; mt < 4; ++mt) {
            unsigned int pk0 = f2bpk(fmaxf(accM[ntl][mt][0], 0.f), fmaxf(accM[ntl][mt][1], 0.f));
            unsigned int pk1 = f2bpk(fmaxf(accM[ntl][mt][2], 0.f), fmaxf(accM[ntl][mt][3], 0.f));
            *(uint2*)&bufR[mt * 16 + ln15][cb] = make_uint2(pk0, pk1);
        }
    }
    __syncthreads();                           // B4 (h_pm visible)

    // ---- pem MFMA (w2pm^T x h) + k-gather prefetch (K-half = sub) ----
    uint4 kpre[4];
    #pragma unroll
    for (int kk = 0; kk < 4; ++kk)
        kpre[kk] = *(const uint4*)(km + (size_t)rg * 256 + (sub * 4 + kk) * 32 + quad * 8);
    {
        f32x4_t b0 = *(const f32x4_t*)(pm_b2 + (w * 2    ) * 16 + quad * 4);
        f32x4_t b1 = *(const f32x4_t*)(pm_b2 + (w * 2 + 1) * 16 + quad * 4);
        for (int mt = 0; mt < 4; ++mt) { acc[0][mt] = b0; acc[1][mt] = b1; }
    }
    __builtin_amdgcn_s_setprio(1);
    #pragma unroll
    for (int kk = 0; kk < 8; ++kk) {
        bf16x8_t afr[4];
        #pragma unroll
        for (int mt = 0; mt < 4; ++mt)
            afr[mt] = *(const bf16x8_t*)&bufR[mt * 16 + ln15][kk * 32 + quad * 8];
        #pragma unroll
        for (int ntl = 0; ntl < 2; ++ntl) {
            int nt = w * 2 + ntl;
            bf16x8_t wfr = *(const bf16x8_t*)(pmw2F + ((nt * 8 + kk) * 64 + lane) * 8);
            #pragma unroll
            for (int mt = 0; mt < 4; ++mt)
                acc[ntl][mt] = __builtin_amdgcn_mfma_f32_16x16x32_bf16(wfr, afr[mt], acc[ntl][mt], 0, 0, 0);
        }
    }
    __builtin_amdgcn_s_setprio(0);
    __syncthreads();                           // B5 (bufR h_pm reads done)

    // ---- q prefetch (K-half) ----
    uint4 qpre[4];
    #pragma unroll
    for (int kk = 0; kk < 4; ++kk)
        qpre[kk] = *(const uint4*)(qm + (size_t)Pg * 256 + (sub * 4 + kk) * 32 + quad * 8);

    // pem epilogue -> bufR
    #pragma unroll
    for (int ntl = 0; ntl < 2; ++ntl) {
        int cb = w * 32 + ntl * 16 + quad * 4;
        #pragma unroll
        for (int mt = 0; mt < 4; ++mt) {
            unsigned int pk0 = f2bpk(acc[ntl][mt][0], acc[ntl][mt][1]);
            unsigned int pk1 = f2bpk(acc[ntl][mt][2], acc[ntl][mt][3]);
            *(uint2*)&bufR[mt * 16 + ln15][cb] = make_uint2(pk0, pk1);
        }
    }
    __syncthreads();                           // B6 (pem/peb visible)

    // ---- relation + partial logits (K-half = sub), swapped MFMA ----
    {
        const bf16x8_t bz = {0, 0, 0, 0, 0, 0, 0, 0};
        f32x4_t lacc = {0.f, 0.f, 0.f, 0.f};
        #pragma unroll
        for (int kk = 0; kk < 4; ++kk) {
            int cb8 = (sub * 4 + kk) * 32 + quad * 8;
            uint4 pm4 = *(const uint4*)&bufR[R0 + ln15][cb8];
            uint4 pb4 = *(const uint4*)&bufP[R0 + ln15][cb8];
            uint4 q4  = qpre[kk];
            union { uint4 u; bf16x8_t v; } rr;
            rr.u.x = relpair(kpre[kk].x, q4.x, pm4.x, pb4.x);
            rr.u.y = relpair(kpre[kk].y, q4.y, pm4.y, pb4.y);
            rr.u.z = relpair(kpre[kk].z, q4.z, pm4.z, pb4.z);
            rr.u.w = relpair(kpre[kk].w, q4.w, pm4.w, pb4.w);
            bf16x8_t wfr = bz;
            if (ln15 < 8) wfr = *(const bf16x8_t*)(we1TF + ln15 * 256 + cb8);
            lacc = __builtin_amdgcn_mfma_f32_16x16x32_bf16(wfr, rr.v, lacc, 0, 0, 0);
        }
        // D[g = quad*4+r][s = ln15]: rows g<8 valid -> quad<2 stores float4
        if (quad < 2)
            *(f32x4_t*)&usP[sub][R0 + ln15][quad * 4] = lacc;
    }

    // ---- v-gather prefetch (acc/accM/afrP/kpre/qpre dead; 16 VGPRs) ----
    const int c5 = (sub * 64 + lane) * 2;      // output cols (2 per lane)
    unsigned int vpre[16];
    #pragma unroll
    for (int s = 0; s < 16; ++s) {
        int rv = rowg_[R0 + s];
        vpre[s] = *(const unsigned int*)(vm + (size_t)rv * 256 + c5);
    }
    __syncthreads();                           // B7 (partials visible)

    // ---- combine + BN/relu + logits2 (even wave, ALL 64 lanes) ----
    // lane = gg*16 + s: computes logits g0=2gg, g0+1 for row s.
    if (sub == 0) {
        int s  = lane & 15, gg = lane >> 4;
        int g0 = gg * 2;
        float2 ua = *(const float2*)&usP[0][R0 + s][g0];
        float2 ub = *(const float2*)&usP[1][R0 + s][g0];
        float2 sw = *(const float2*)&swe8[g0];
        float2 dw = *(const float2*)&dwe8[g0];
        float u0 = fmaxf((ua.x + ub.x) * sw.x + dw.x, 0.f);
        float u1 = fmaxf((ua.y + ub.y) * sw.y + dw.y, 0.f);
        // gather the other 6 uv values for this s (lanes s, s+16, s+32, s+48)
        float p0 = __shfl_xor(u0, 16), p1 = __shfl_xor(u1, 16);   // g0^2 pair
        float q0 = __shfl_xor(u0, 32), q1 = __shfl_xor(u1, 32);   // g0^4 pair
        float r0 = __shfl_xor(p0, 32), r1 = __shfl_xor(p1, 32);   // g0^6 pair
        int ga = g0 ^ 2, gb = g0 ^ 4, gc = g0 ^ 6;
        float l0 = web2[g0], l1 = web2[g0 + 1];
        float2 wv2;
        wv2 = *(const float2*)&we2s[g0][g0];     l0 += u0 * wv2.x; l1 += u0 * wv2.y;
        wv2 = *(const float2*)&we2s[g0 + 1][g0]; l0 += u1 * wv2.x; l1 += u1 * wv2.y;
        wv2 = *(const float2*)&we2s[ga][g0];     l0 += p0 * wv2.x; l1 += p0 * wv2.y;
        wv2 = *(const float2*)&we2s[ga + 1][g0]; l0 += p1 * wv2.x; l1 += p1 * wv2.y;
        wv2 = *(const float2*)&we2s[gb][g0];     l0 += q0 * wv2.x; l1 += q0 * wv2.y;
        wv2 = *(const float2*)&we2s[gb + 1][g0]; l0 += q1 * wv2.x; l1 += q1 * wv2.y;
        wv2 = *(const float2*)&we2s[gc][g0];     l0 += r0 * wv2.x; l1 += r0 * wv2.y;
        wv2 = *(const float2*)&we2s[gc + 1][g0]; l0 += r1 * wv2.x; l1 += r1 * wv2.y;
        *(float2*)&us_[R0 + s][g0] = make_float2(l0, l1);
    }
    WSYNC();

    // ---- softmax over s (even wave, ALL 64 lanes; lane = sh*8 + g) ----
    if (sub == 0) {
        int g = lane & 7, sh = lane >> 3;      // sh 0..7 -> s = 2sh, 2sh+1
        int s0 = sh * 2;
        float a = us_[R0 + s0][g], b = us_[R0 + s0 + 1][g];
        float mx = fmaxf(a, b);
        mx = fmaxf(mx, __shfl_xor(mx, 8));
        mx = fmaxf(mx, __shfl_xor(mx, 16));
        mx = fmaxf(mx, __shfl_xor(mx, 32));
        float ea = __expf(a - mx), eb = __expf(b - mx);
        float sm = ea + eb;
        sm += __shfl_xor(sm, 8);
        sm += __shfl_xor(sm, 16);
        sm += __shfl_xor(sm, 32);
        float inv = 1.f / sm;
        us_[R0 + s0][g]     = ea * inv;
        us_[R0 + s0 + 1][g] = eb * inv;
    }
    __syncthreads();                           // B8 (softmax visible)

    // ---- output: wave pair = 128 lanes, 2 cols each ----
    {
        int g = c5 >> 5;
        float a0 = 0.f, a1 = 0.f;
        #pragma unroll
        for (int s = 0; s < 16; ++s) {
            float wv_ = us_[R0 + s][g];
            unsigned int v2 = vpre[s];
            unsigned int p2 = *(const unsigned int*)&bufP[R0 + s][c5];
            a0 += wv_ * (blo(v2) + blo(p2));
            a1 += wv_ * (bhi(v2) + bhi(p2));
        }
        *(float2*)(out + (size_t)Pg * 256 + c5) = make_float2(a0, a1);
    }
}

// ---------------------------------------------------------------------------
extern "C" void kernel_launch(void* const* d_in, const int* in_sizes, int n_in,
                              void* d_out, int out_size, void* d_ws, size_t ws_size,
                              hipStream_t stream)
{
    const float* feats  = (const float*)d_in[0];
    const float* coords = (const float*)d_in[1];
    const int*   index  = (const int*)d_in[2];
    const float* wq     = (const float*)d_in[3];
    const float* bq     = (const float*)d_in[4];
    const float* bnq    = (const float*)d_in[5];
    const float* wk     = (const float*)d_in[6];
    const float* bk     = (const float*)d_in[7];
    const float* bnk    = (const float*)d_in[8];
    const float* wv     = (const float*)d_in[9];
    const float* bv     = (const float*)d_in[10];
    const float* pm_w1  = (const float*)d_in[11];
    const float* pm_b1  = (const float*)d_in[12];
    const float* pm_bn  = (const float*)d_in[13];
    const float* pm_w2  = (const float*)d_in[14];
    const float* pm_b2  = (const float*)d_in[15];
    const float* pb_w1  = (const float*)d_in[16];
    const float* pb_b1  = (const float*)d_in[17];
    const float* pb_bn  = (const float*)d_in[18];
    const float* pb_w2  = (const float*)d_in[19];
    const float* pb_b2  = (const float*)d_in[20];
    const float* we_w1  = (const float*)d_in[21];
    const float* we_b1  = (const float*)d_in[22];
    const float* we_bn  = (const float*)d_in[23];
    const float* we_w2  = (const float*)d_in[24];
    const float* we_b2  = (const float*)d_in[25];

    unsigned short* qkv   = (unsigned short*)d_ws;
    unsigned short* wsT   = qkv + (size_t)3 * 8192 * 256;
    unsigned short* we1TF = wsT + 5 * 65536;
    unsigned short* w1F   = we1TF + 2048;
    float*          SS    = (float*)(w1F + 16384);

    const size_t need = (size_t)13281280;
    if (ws_size < need) {
        hipMemsetAsync(d_out, 0, (size_t)out_size * 4, stream);
        return;
    }

    k_prep<<<162,  256, 0, stream>>>(wq, wk, wv, pm_w2, pb_w2,
                                     pm_w1, pm_b1, pm_bn,
                                     pb_w1, pb_b1, pb_bn,
                                     we_w1,
                                     bq, bnq, bk, bnk, bv,
                                     wsT, w1F, we1TF, SS);
    k_qkv <<<768,  256, 0, stream>>>(feats, wsT, SS, qkv);
    k_main<<<2048, 512, 0, stream>>>(coords, index,
                                     qkv,
                                     qkv + (size_t)8192 * 256,
                                     qkv + (size_t)2 * 8192 * 256,
                                     wsT + 3 * 65536,
                                     wsT + 4 * 65536,
                                     w1F, we1TF,
                                     pm_b2, pb_b2,
                                     we_b1, we_bn, we_w2, we_b2,
                                     (float*)d_out);
}